// Round 1
// baseline (2422.324 us; speedup 1.0000x reference)
//
#include <hip/hip_runtime.h>

#define NN 50000
#define NE 800000
#define NG 64
#define NODE_F 11
#define EDGE_F 14
#define HD 128
#define NL 3
#define BN_EPS 1e-5f

// ---------------- node embedding: h = x @ node_W^T + node_b ----------------
__global__ __launch_bounds__(256)
void node_embed_kernel(const float* __restrict__ x, const float* __restrict__ W,
                       const float* __restrict__ b, float* __restrict__ h, int n)
{
    int idx = blockIdx.x * 256 + threadIdx.x;
    if (idx >= n * HD) return;
    int node = idx >> 7, c = idx & 127;
    const float* xr = x + node * NODE_F;
    const float* wr = W + c * NODE_F;
    float acc = b[c];
#pragma unroll
    for (int f = 0; f < NODE_F; ++f) acc += xr[f] * wr[f];
    h[idx] = acc;
}

// ------------- transpose the 7 128x128 weight matrices into ws -------------
// wt[m][k][co] = W_m[co][k]   (m: 0..2 lin1, 3..5 lin2, 6 proj)
__global__ __launch_bounds__(256)
void transpose_kernel(const float* __restrict__ lin1, const float* __restrict__ lin2,
                      const float* __restrict__ proj, float* __restrict__ wt)
{
    int idx = blockIdx.x * 256 + threadIdx.x;
    if (idx >= 7 * HD * HD) return;
    int m = idx >> 14, e = idx & (HD * HD - 1);
    int r = e >> 7, c = e & 127;
    const float* src = (m < 3) ? (lin1 + m * HD * HD)
                    : ((m < 6) ? (lin2 + (m - 3) * HD * HD) : proj);
    wt[m * HD * HD + c * HD + r] = src[r * HD + c];
}

// ---- fused message + scatter: agg[dst] += relu(h[src] + edge_embed(e)) ----
// 1 wave per edge, each lane handles 2 consecutive channels (float2).
__global__ __launch_bounds__(256)
void edge_kernel(const float* __restrict__ h, const int* __restrict__ ei,
                 const float* __restrict__ ea, const float* __restrict__ eW,
                 const float* __restrict__ eb, float* __restrict__ agg, int E)
{
    __shared__ __align__(16) float wts[EDGE_F][HD];  // transposed edge_W
    __shared__ float blds[HD];
    for (int idx = threadIdx.x; idx < EDGE_F * HD; idx += 256) {
        int c = idx / EDGE_F, f = idx % EDGE_F;
        wts[f][c] = eW[idx];
    }
    if (threadIdx.x < HD) blds[threadIdx.x] = eb[threadIdx.x];
    __syncthreads();
    int e = blockIdx.x * 4 + (threadIdx.x >> 6);
    if (e >= E) return;
    int lane = threadIdx.x & 63;
    int s = ei[e], d = ei[E + e];
    int c2 = lane * 2;
    float2 hv = *(const float2*)&h[s * HD + c2];
    float ax = blds[c2], ay = blds[c2 + 1];
    const float* ear = ea + e * EDGE_F;
#pragma unroll
    for (int f = 0; f < EDGE_F; ++f) {
        float av = ear[f];
        float2 w = *(const float2*)&wts[f][c2];
        ax += av * w.x; ay += av * w.y;
    }
    float mx = fmaxf(hv.x + ax, 0.f);
    float my = fmaxf(hv.y + ay, 0.f);
    atomicAdd(&agg[d * HD + c2], mx);
    atomicAdd(&agg[d * HD + c2 + 1], my);
}

// --------------- dense layer GEMM: 64-node tile, 128x128 weight ------------
// MODE 0: out = relu(BN((a+add) @ Wt + bias))        (lin1 + BN + relu)
// MODE 1: out = relu(a @ Wt + bias) + resid          (lin2 + relu + residual)
template <int MODE>
__global__ __launch_bounds__(256)
void gemm_kernel(const float* __restrict__ a, const float* __restrict__ add_,
                 const float* __restrict__ Wt, const float* __restrict__ bias,
                 const float* __restrict__ gamma, const float* __restrict__ beta,
                 const float* __restrict__ mean, const float* __restrict__ var,
                 const float* __restrict__ resid, float* __restrict__ out, int n)
{
    __shared__ __align__(16) float in_lds[64][132];  // [node][k], pad 132 -> no conflicts
    const int t = threadIdx.x;
    const int nb = blockIdx.x * 64;
    for (int idx = t; idx < 64 * HD; idx += 256) {
        int nn = idx >> 7, k = idx & 127;
        int gn = nb + nn;
        float v = 0.f;
        if (gn < n) {
            v = a[gn * HD + k];
            if (MODE == 0) v += add_[gn * HD + k];
        }
        in_lds[nn][k] = v;
    }
    __syncthreads();
    const int c0 = (t & 31) * 4;   // 4 output channels
    const int n0 = (t >> 5) * 8;   // 8 nodes
    float acc[8][4];
#pragma unroll
    for (int j = 0; j < 8; ++j)
#pragma unroll
        for (int c = 0; c < 4; ++c) acc[j][c] = 0.f;

    for (int k0 = 0; k0 < HD; k0 += 4) {
        float4 w0 = *(const float4*)&Wt[(k0 + 0) * HD + c0];
        float4 w1 = *(const float4*)&Wt[(k0 + 1) * HD + c0];
        float4 w2 = *(const float4*)&Wt[(k0 + 2) * HD + c0];
        float4 w3 = *(const float4*)&Wt[(k0 + 3) * HD + c0];
#pragma unroll
        for (int j = 0; j < 8; ++j) {
            float4 xv = *(const float4*)&in_lds[n0 + j][k0];
            acc[j][0] += xv.x * w0.x; acc[j][1] += xv.x * w0.y; acc[j][2] += xv.x * w0.z; acc[j][3] += xv.x * w0.w;
            acc[j][0] += xv.y * w1.x; acc[j][1] += xv.y * w1.y; acc[j][2] += xv.y * w1.z; acc[j][3] += xv.y * w1.w;
            acc[j][0] += xv.z * w2.x; acc[j][1] += xv.z * w2.y; acc[j][2] += xv.z * w2.z; acc[j][3] += xv.z * w2.w;
            acc[j][0] += xv.w * w3.x; acc[j][1] += xv.w * w3.y; acc[j][2] += xv.w * w3.z; acc[j][3] += xv.w * w3.w;
        }
    }
    float bi[4] = {bias[c0], bias[c0 + 1], bias[c0 + 2], bias[c0 + 3]};
    float sc[4], sh[4];
    if (MODE == 0) {
#pragma unroll
        for (int c = 0; c < 4; ++c) {
            float s = gamma[c0 + c] * rsqrtf(var[c0 + c] + BN_EPS);
            sc[c] = s;
            sh[c] = beta[c0 + c] - mean[c0 + c] * s;
        }
    }
#pragma unroll
    for (int j = 0; j < 8; ++j) {
        int gn = nb + n0 + j;
        if (gn < n) {
            float vals[4];
#pragma unroll
            for (int c = 0; c < 4; ++c) {
                float v = acc[j][c] + bi[c];
                if (MODE == 0) v = v * sc[c] + sh[c];
                v = fmaxf(v, 0.f);
                vals[c] = v;
            }
            if (MODE == 1) {
                float4 r = *(const float4*)&resid[gn * HD + c0];
                vals[0] += r.x; vals[1] += r.y; vals[2] += r.z; vals[3] += r.w;
            }
            float4 o = {vals[0], vals[1], vals[2], vals[3]};
            *(float4*)&out[gn * HD + c0] = o;
        }
    }
}

// -------- pooling: sorted batch_idx -> chunked local sums, rare atomics ----
__global__ __launch_bounds__(128)
void pool_kernel(const float* __restrict__ h, const int* __restrict__ batch,
                 float* __restrict__ pooled, int* __restrict__ counts, int n, int chunk)
{
    int c = threadIdx.x;
    int n_start = blockIdx.x * chunk;
    if (n_start >= n) return;
    int n_end = min(n_start + chunk, n);
    float local = 0.f;
    int cnt = 0;
    int g_cur = batch[n_start];
    for (int nd = n_start; nd < n_end; ++nd) {
        int g = batch[nd];
        if (g != g_cur) {
            atomicAdd(&pooled[g_cur * HD + c], local);
            if (c == 0) atomicAdd(&counts[g_cur], cnt);
            local = 0.f; cnt = 0; g_cur = g;
        }
        local += h[nd * HD + c];
        cnt++;
    }
    atomicAdd(&pooled[g_cur * HD + c], local);
    if (c == 0) atomicAdd(&counts[g_cur], cnt);
}

// ---------------- final: out[g] = (pooled[g]/cnt) @ proj^T + b -------------
__global__ __launch_bounds__(128)
void final_kernel(const float* __restrict__ pooled, const int* __restrict__ counts,
                  const float* __restrict__ projT, const float* __restrict__ pb,
                  float* __restrict__ out)
{
    __shared__ float p_lds[HD];
    int g = blockIdx.x, p = threadIdx.x;
    float inv = 1.f / fmaxf((float)counts[g], 1.f);
    p_lds[p] = pooled[g * HD + p];
    __syncthreads();
    float acc = 0.f;
#pragma unroll 4
    for (int c = 0; c < HD; ++c) acc += p_lds[c] * projT[c * HD + p];
    out[g * HD + p] = acc * inv + pb[p];
}

extern "C" void kernel_launch(void* const* d_in, const int* in_sizes, int n_in,
                              void* d_out, int out_size, void* d_ws, size_t ws_size,
                              hipStream_t stream)
{
    const float* x        = (const float*)d_in[0];
    const int*   edge_idx = (const int*)d_in[1];
    const float* edge_attr= (const float*)d_in[2];
    const int*   batch    = (const int*)d_in[3];
    const float* node_W   = (const float*)d_in[4];
    const float* node_b   = (const float*)d_in[5];
    const float* edge_W   = (const float*)d_in[6];
    const float* edge_b   = (const float*)d_in[7];
    const float* lin1_W   = (const float*)d_in[8];
    const float* lin1_b   = (const float*)d_in[9];
    const float* bn_gamma = (const float*)d_in[10];
    const float* bn_beta  = (const float*)d_in[11];
    const float* bn_mean  = (const float*)d_in[12];
    const float* bn_var   = (const float*)d_in[13];
    const float* lin2_W   = (const float*)d_in[14];
    const float* lin2_b   = (const float*)d_in[15];
    const float* proj_b   = (const float*)d_in[17];

    char* ws = (char*)d_ws;
    float* h      = (float*)(ws);                 // 25.6 MB
    float* agg    = (float*)(ws + 25600000);      // 25.6 MB
    float* z      = (float*)(ws + 51200000);      // 25.6 MB
    float* wt     = (float*)(ws + 76800000);      // 7*16384 floats
    float* pooled = (float*)(ws + 77258752);      // 32 KB
    int*   counts = (int*)(ws + 77291520);        // 256 B

    transpose_kernel<<<(7 * HD * HD + 255) / 256, 256, 0, stream>>>(
        lin1_W, lin2_W, (const float*)d_in[16], wt);
    node_embed_kernel<<<(NN * HD + 255) / 256, 256, 0, stream>>>(x, node_W, node_b, h, NN);

    for (int i = 0; i < NL; ++i) {
        hipMemsetAsync(agg, 0, (size_t)NN * HD * sizeof(float), stream);
        edge_kernel<<<(NE + 3) / 4, 256, 0, stream>>>(h, edge_idx, edge_attr, edge_W, edge_b, agg, NE);
        gemm_kernel<0><<<(NN + 63) / 64, 256, 0, stream>>>(
            h, agg, wt + i * HD * HD, lin1_b + i * HD,
            bn_gamma + i * HD, bn_beta + i * HD, bn_mean + i * HD, bn_var + i * HD,
            nullptr, z, NN);
        gemm_kernel<1><<<(NN + 63) / 64, 256, 0, stream>>>(
            z, nullptr, wt + (3 + i) * HD * HD, lin2_b + i * HD,
            nullptr, nullptr, nullptr, nullptr, h, h, NN);
    }

    hipMemsetAsync(pooled, 0, NG * HD * sizeof(float), stream);
    hipMemsetAsync(counts, 0, NG * sizeof(int), stream);
    pool_kernel<<<(NN + 255) / 256, 128, 0, stream>>>(h, batch, pooled, counts, NN, 256);
    final_kernel<<<NG, HD, 0, stream>>>(pooled, counts, wt + 6 * HD * HD, proj_b, (float*)d_out);
}

// Round 2
// 969.614 us; speedup vs baseline: 2.4982x; 2.4982x over previous
//
#include <hip/hip_runtime.h>

#define NN 50000
#define NE 800000
#define NG 64
#define NODE_F 11
#define EDGE_F 14
#define HD 128
#define NL 3
#define BN_EPS 1e-5f

// ---------------- node embedding: h = x @ node_W^T + node_b ----------------
__global__ __launch_bounds__(256)
void node_embed_kernel(const float* __restrict__ x, const float* __restrict__ W,
                       const float* __restrict__ b, float* __restrict__ h, int n)
{
    int idx = blockIdx.x * 256 + threadIdx.x;
    if (idx >= n * HD) return;
    int node = idx >> 7, c = idx & 127;
    const float* xr = x + node * NODE_F;
    const float* wr = W + c * NODE_F;
    float acc = b[c];
#pragma unroll
    for (int f = 0; f < NODE_F; ++f) acc += xr[f] * wr[f];
    h[idx] = acc;
}

// ------------- transpose the 7 128x128 weight matrices into ws -------------
__global__ __launch_bounds__(256)
void transpose_kernel(const float* __restrict__ lin1, const float* __restrict__ lin2,
                      const float* __restrict__ proj, float* __restrict__ wt)
{
    int idx = blockIdx.x * 256 + threadIdx.x;
    if (idx >= 7 * HD * HD) return;
    int m = idx >> 14, e = idx & (HD * HD - 1);
    int r = e >> 7, c = e & 127;
    const float* src = (m < 3) ? (lin1 + m * HD * HD)
                    : ((m < 6) ? (lin2 + (m - 3) * HD * HD) : proj);
    wt[m * HD * HD + c * HD + r] = src[r * HD + c];
}

// ----------------------------- CSR construction ----------------------------
__global__ __launch_bounds__(256)
void hist_kernel(const int* __restrict__ ei, int* __restrict__ deg)
{
    int e = blockIdx.x * 256 + threadIdx.x;
    if (e < NE) atomicAdd(&deg[ei[NE + e]], 1);
}

__global__ __launch_bounds__(256)
void scan1_kernel(const int* __restrict__ deg, int* __restrict__ incl, int* __restrict__ bsum)
{
    int i = blockIdx.x * 256 + threadIdx.x;
    int v = (i < NN) ? deg[i] : 0;
    int lane = threadIdx.x & 63;
#pragma unroll
    for (int off = 1; off < 64; off <<= 1) {
        int u = __shfl_up(v, off);
        if (lane >= off) v += u;
    }
    __shared__ int wsum[4];
    if (lane == 63) wsum[threadIdx.x >> 6] = v;
    __syncthreads();
    int wid = threadIdx.x >> 6;
    int add = 0;
#pragma unroll
    for (int w = 0; w < 3; ++w) if (w < wid) add += wsum[w];
    v += add;
    if (i < NN) incl[i] = v;
    if (threadIdx.x == 255) bsum[blockIdx.x] = v;
}

__global__ __launch_bounds__(256)
void scan2_kernel(const int* __restrict__ bsum, int* __restrict__ bscan, int nb)
{
    int i = threadIdx.x;
    int v = (i < nb) ? bsum[i] : 0;
    int lane = i & 63;
#pragma unroll
    for (int off = 1; off < 64; off <<= 1) {
        int u = __shfl_up(v, off);
        if (lane >= off) v += u;
    }
    __shared__ int wsum[4];
    if (lane == 63) wsum[i >> 6] = v;
    __syncthreads();
    int wid = i >> 6;
    int add = 0;
#pragma unroll
    for (int w = 0; w < 3; ++w) if (w < wid) add += wsum[w];
    v += add;
    bscan[i] = v;
}

__global__ __launch_bounds__(256)
void scan3_kernel(const int* __restrict__ deg, const int* __restrict__ incl,
                  const int* __restrict__ bscan, int* __restrict__ row_start,
                  int* __restrict__ cursor)
{
    int i = blockIdx.x * 256 + threadIdx.x;
    if (i >= NN) return;
    int b = blockIdx.x;
    int base = (b > 0) ? bscan[b - 1] : 0;
    int rs = base + incl[i] - deg[i];
    row_start[i] = rs;
    cursor[i] = rs;
    if (i == 0) row_start[NN] = NE;
}

__global__ __launch_bounds__(256)
void scatter_kernel(const int* __restrict__ ei, int* __restrict__ cursor,
                    int2* __restrict__ pairs)
{
    int e = blockIdx.x * 256 + threadIdx.x;
    if (e >= NE) return;
    int s = ei[e], d = ei[NE + e];
    int pos = atomicAdd(&cursor[d], 1);
    pairs[pos] = make_int2(s, e);
}

// ------ gather aggregation: zin[n] = h[n] + sum_{e->n} relu(h[src]+emb) ----
// one wave per node, each lane owns 2 channels; edge weights in registers.
__global__ __launch_bounds__(256)
void agg_kernel(const float* __restrict__ h, const int2* __restrict__ pairs,
                const int* __restrict__ row_start, const float* __restrict__ ea,
                const float* __restrict__ eW, const float* __restrict__ eb,
                float* __restrict__ zin)
{
    int node = blockIdx.x * 4 + (threadIdx.x >> 6);
    if (node >= NN) return;
    int lane = threadIdx.x & 63;
    int c2 = lane * 2;
    float w0[EDGE_F], w1[EDGE_F];
    {
        const float* p = eW + c2 * EDGE_F;
#pragma unroll
        for (int f = 0; f < EDGE_F; ++f) { w0[f] = p[f]; w1[f] = p[EDGE_F + f]; }
    }
    float bx = eb[c2], by = eb[c2 + 1];
    float accx = 0.f, accy = 0.f;
    int beg = row_start[node], end = row_start[node + 1];
    for (int j = beg; j < end; ++j) {
        int2 se = pairs[j];
        float2 hv = *(const float2*)&h[(size_t)se.x * HD + c2];
        const float2* er2 = (const float2*)(ea + (size_t)se.y * EDGE_F);
        float ax = bx, ay = by;
#pragma unroll
        for (int f2 = 0; f2 < 7; ++f2) {
            float2 av = er2[f2];
            ax += av.x * w0[2 * f2] + av.y * w0[2 * f2 + 1];
            ay += av.x * w1[2 * f2] + av.y * w1[2 * f2 + 1];
        }
        accx += fmaxf(hv.x + ax, 0.f);
        accy += fmaxf(hv.y + ay, 0.f);
    }
    float2 hn = *(const float2*)&h[(size_t)node * HD + c2];
    float2 o = { hn.x + accx, hn.y + accy };
    *(float2*)&zin[(size_t)node * HD + c2] = o;
}

// --------------- dense layer GEMM: 64-node tile, 128x128 weight ------------
// MODE 0: out = relu(BN(a @ Wt + bias))            (lin1 + BN + relu)
// MODE 1: out = relu(a @ Wt + bias) + resid        (lin2 + relu + residual)
template <int MODE>
__global__ __launch_bounds__(256)
void gemm_kernel(const float* __restrict__ a, const float* __restrict__ Wt,
                 const float* __restrict__ bias,
                 const float* __restrict__ gamma, const float* __restrict__ beta,
                 const float* __restrict__ mean, const float* __restrict__ var,
                 const float* __restrict__ resid, float* __restrict__ out, int n)
{
    __shared__ __align__(16) float in_lds[64][132];
    const int t = threadIdx.x;
    const int nb = blockIdx.x * 64;
    for (int idx = t; idx < 64 * HD; idx += 256) {
        int nn = idx >> 7, k = idx & 127;
        int gn = nb + nn;
        in_lds[nn][k] = (gn < n) ? a[(size_t)gn * HD + k] : 0.f;
    }
    __syncthreads();
    const int c0 = (t & 31) * 4;
    const int n0 = (t >> 5) * 8;
    float acc[8][4];
#pragma unroll
    for (int j = 0; j < 8; ++j)
#pragma unroll
        for (int c = 0; c < 4; ++c) acc[j][c] = 0.f;

    for (int k0 = 0; k0 < HD; k0 += 4) {
        float4 w0 = *(const float4*)&Wt[(k0 + 0) * HD + c0];
        float4 w1 = *(const float4*)&Wt[(k0 + 1) * HD + c0];
        float4 w2 = *(const float4*)&Wt[(k0 + 2) * HD + c0];
        float4 w3 = *(const float4*)&Wt[(k0 + 3) * HD + c0];
#pragma unroll
        for (int j = 0; j < 8; ++j) {
            float4 xv = *(const float4*)&in_lds[n0 + j][k0];
            acc[j][0] += xv.x * w0.x; acc[j][1] += xv.x * w0.y; acc[j][2] += xv.x * w0.z; acc[j][3] += xv.x * w0.w;
            acc[j][0] += xv.y * w1.x; acc[j][1] += xv.y * w1.y; acc[j][2] += xv.y * w1.z; acc[j][3] += xv.y * w1.w;
            acc[j][0] += xv.z * w2.x; acc[j][1] += xv.z * w2.y; acc[j][2] += xv.z * w2.z; acc[j][3] += xv.z * w2.w;
            acc[j][0] += xv.w * w3.x; acc[j][1] += xv.w * w3.y; acc[j][2] += xv.w * w3.z; acc[j][3] += xv.w * w3.w;
        }
    }
    float bi[4] = {bias[c0], bias[c0 + 1], bias[c0 + 2], bias[c0 + 3]};
    float sc[4], sh[4];
    if (MODE == 0) {
#pragma unroll
        for (int c = 0; c < 4; ++c) {
            float s = gamma[c0 + c] * rsqrtf(var[c0 + c] + BN_EPS);
            sc[c] = s;
            sh[c] = beta[c0 + c] - mean[c0 + c] * s;
        }
    }
#pragma unroll
    for (int j = 0; j < 8; ++j) {
        int gn = nb + n0 + j;
        if (gn < n) {
            float vals[4];
#pragma unroll
            for (int c = 0; c < 4; ++c) {
                float v = acc[j][c] + bi[c];
                if (MODE == 0) v = v * sc[c] + sh[c];
                v = fmaxf(v, 0.f);
                vals[c] = v;
            }
            if (MODE == 1) {
                float4 r = *(const float4*)&resid[(size_t)gn * HD + c0];
                vals[0] += r.x; vals[1] += r.y; vals[2] += r.z; vals[3] += r.w;
            }
            float4 o = {vals[0], vals[1], vals[2], vals[3]};
            *(float4*)&out[(size_t)gn * HD + c0] = o;
        }
    }
}

// -------- pooling: sorted batch_idx -> chunked local sums, rare atomics ----
__global__ __launch_bounds__(128)
void pool_kernel(const float* __restrict__ h, const int* __restrict__ batch,
                 float* __restrict__ pooled, int* __restrict__ counts, int n, int chunk)
{
    int c = threadIdx.x;
    int n_start = blockIdx.x * chunk;
    if (n_start >= n) return;
    int n_end = min(n_start + chunk, n);
    float local = 0.f;
    int cnt = 0;
    int g_cur = batch[n_start];
    for (int nd = n_start; nd < n_end; ++nd) {
        int g = batch[nd];
        if (g != g_cur) {
            atomicAdd(&pooled[g_cur * HD + c], local);
            if (c == 0) atomicAdd(&counts[g_cur], cnt);
            local = 0.f; cnt = 0; g_cur = g;
        }
        local += h[(size_t)nd * HD + c];
        cnt++;
    }
    atomicAdd(&pooled[g_cur * HD + c], local);
    if (c == 0) atomicAdd(&counts[g_cur], cnt);
}

__global__ __launch_bounds__(128)
void final_kernel(const float* __restrict__ pooled, const int* __restrict__ counts,
                  const float* __restrict__ projT, const float* __restrict__ pb,
                  float* __restrict__ out)
{
    __shared__ float p_lds[HD];
    int g = blockIdx.x, p = threadIdx.x;
    float inv = 1.f / fmaxf((float)counts[g], 1.f);
    p_lds[p] = pooled[g * HD + p];
    __syncthreads();
    float acc = 0.f;
#pragma unroll 4
    for (int c = 0; c < HD; ++c) acc += p_lds[c] * projT[c * HD + p];
    out[g * HD + p] = acc * inv + pb[p];
}

extern "C" void kernel_launch(void* const* d_in, const int* in_sizes, int n_in,
                              void* d_out, int out_size, void* d_ws, size_t ws_size,
                              hipStream_t stream)
{
    const float* x        = (const float*)d_in[0];
    const int*   edge_idx = (const int*)d_in[1];
    const float* edge_attr= (const float*)d_in[2];
    const int*   batch    = (const int*)d_in[3];
    const float* node_W   = (const float*)d_in[4];
    const float* node_b   = (const float*)d_in[5];
    const float* edge_W   = (const float*)d_in[6];
    const float* edge_b   = (const float*)d_in[7];
    const float* lin1_W   = (const float*)d_in[8];
    const float* lin1_b   = (const float*)d_in[9];
    const float* bn_gamma = (const float*)d_in[10];
    const float* bn_beta  = (const float*)d_in[11];
    const float* bn_mean  = (const float*)d_in[12];
    const float* bn_var   = (const float*)d_in[13];
    const float* lin2_W   = (const float*)d_in[14];
    const float* lin2_b   = (const float*)d_in[15];
    const float* proj_b   = (const float*)d_in[17];

    char* ws = (char*)d_ws;
    float* h        = (float*)(ws);                  // 25,600,000
    float* zin      = (float*)(ws + 25600000);       // 25,600,000 (also z, in-place)
    float* wt       = (float*)(ws + 51200000);       // 458,752
    float* pooled   = (float*)(ws + 51658752);       // 32,768
    int*   counts   = (int*)  (ws + 51691520);       // 256
    int*   deg      = (int*)  (ws + 51691776);       // 200,000
    int*   incl     = (int*)  (ws + 51891776);       // 200,000
    int*   bsum     = (int*)  (ws + 52091776);       // 1,024
    int*   bscan    = (int*)  (ws + 52092800);       // 1,024
    int*   row_start= (int*)  (ws + 52093824);       // 200,064
    int*   cursor   = (int*)  (ws + 52293888);       // 200,000
    int2*  pairs    = (int2*) (ws + 52493888);       // 6,400,000

    const int NB = (NN + 255) / 256;  // 196

    // --- CSR build (edge_index is constant across layers) ---
    hipMemsetAsync(deg, 0, NN * sizeof(int), stream);
    hist_kernel<<<(NE + 255) / 256, 256, 0, stream>>>(edge_idx, deg);
    scan1_kernel<<<NB, 256, 0, stream>>>(deg, incl, bsum);
    scan2_kernel<<<1, 256, 0, stream>>>(bsum, bscan, NB);
    scan3_kernel<<<NB, 256, 0, stream>>>(deg, incl, bscan, row_start, cursor);
    scatter_kernel<<<(NE + 255) / 256, 256, 0, stream>>>(edge_idx, cursor, pairs);

    transpose_kernel<<<(7 * HD * HD + 255) / 256, 256, 0, stream>>>(
        lin1_W, lin2_W, (const float*)d_in[16], wt);
    node_embed_kernel<<<(NN * HD + 255) / 256, 256, 0, stream>>>(x, node_W, node_b, h, NN);

    for (int i = 0; i < NL; ++i) {
        agg_kernel<<<(NN + 3) / 4, 256, 0, stream>>>(
            h, pairs, row_start, edge_attr, edge_W, edge_b, zin);
        gemm_kernel<0><<<(NN + 63) / 64, 256, 0, stream>>>(
            zin, wt + i * HD * HD, lin1_b + i * HD,
            bn_gamma + i * HD, bn_beta + i * HD, bn_mean + i * HD, bn_var + i * HD,
            nullptr, zin, NN);
        gemm_kernel<1><<<(NN + 63) / 64, 256, 0, stream>>>(
            zin, wt + (3 + i) * HD * HD, lin2_b + i * HD,
            nullptr, nullptr, nullptr, nullptr, h, h, NN);
    }

    hipMemsetAsync(pooled, 0, NG * HD * sizeof(float), stream);
    hipMemsetAsync(counts, 0, NG * sizeof(int), stream);
    pool_kernel<<<NB, 128, 0, stream>>>(h, batch, pooled, counts, NN, 256);
    final_kernel<<<NG, HD, 0, stream>>>(pooled, counts, wt + 6 * HD * HD, proj_b, (float*)d_out);
}

// Round 3
// 635.515 us; speedup vs baseline: 3.8116x; 1.5257x over previous
//
#include <hip/hip_runtime.h>

typedef unsigned int uint;

#define NN 50000
#define NE 800000
#define NG 64
#define NODE_F 11
#define EDGE_F 14
#define HD 128
#define NL 3
#define BN_EPS 1e-5f

__device__ __forceinline__ uint bfround(float v) {
    uint b = __float_as_uint(v);
    return (b + 0x7fffu + ((b >> 16) & 1u)) >> 16;
}

// -------- node embedding: h = x @ node_W^T + node_b (+ bf16 shadow) --------
__global__ __launch_bounds__(256)
void node_embed_kernel(const float* __restrict__ x, const float* __restrict__ W,
                       const float* __restrict__ b, float* __restrict__ h,
                       uint* __restrict__ hb, int n)
{
    int idx = blockIdx.x * 256 + threadIdx.x;
    if (idx >= n * 64) return;
    int node = idx >> 6, cp = idx & 63;
    int c2 = cp * 2;
    const float* xr = x + node * NODE_F;
    const float* w0 = W + c2 * NODE_F;
    const float* w1 = w0 + NODE_F;
    float a0 = b[c2], a1 = b[c2 + 1];
#pragma unroll
    for (int f = 0; f < NODE_F; ++f) { float xv = xr[f]; a0 += xv * w0[f]; a1 += xv * w1[f]; }
    *(float2*)&h[(size_t)node * HD + c2] = make_float2(a0, a1);
    hb[idx] = bfround(a0) | (bfround(a1) << 16);
}

// ------------- transpose the 7 128x128 weight matrices into ws -------------
__global__ __launch_bounds__(256)
void transpose_kernel(const float* __restrict__ lin1, const float* __restrict__ lin2,
                      const float* __restrict__ proj, float* __restrict__ wt)
{
    int idx = blockIdx.x * 256 + threadIdx.x;
    if (idx >= 7 * HD * HD) return;
    int m = idx >> 14, e = idx & (HD * HD - 1);
    int r = e >> 7, c = e & 127;
    const float* src = (m < 3) ? (lin1 + m * HD * HD)
                    : ((m < 6) ? (lin2 + (m - 3) * HD * HD) : proj);
    wt[m * HD * HD + c * HD + r] = src[r * HD + c];
}

// ----------------------------- CSR construction ----------------------------
__global__ __launch_bounds__(256)
void hist_kernel(const int* __restrict__ ei, int* __restrict__ deg)
{
    int e = blockIdx.x * 256 + threadIdx.x;
    if (e < NE) atomicAdd(&deg[ei[NE + e]], 1);
}

__global__ __launch_bounds__(256)
void scan1_kernel(const int* __restrict__ deg, int* __restrict__ incl, int* __restrict__ bsum)
{
    int i = blockIdx.x * 256 + threadIdx.x;
    int v = (i < NN) ? deg[i] : 0;
    int lane = threadIdx.x & 63;
#pragma unroll
    for (int off = 1; off < 64; off <<= 1) {
        int u = __shfl_up(v, off);
        if (lane >= off) v += u;
    }
    __shared__ int wsum[4];
    if (lane == 63) wsum[threadIdx.x >> 6] = v;
    __syncthreads();
    int wid = threadIdx.x >> 6;
    int add = 0;
#pragma unroll
    for (int w = 0; w < 3; ++w) if (w < wid) add += wsum[w];
    v += add;
    if (i < NN) incl[i] = v;
    if (threadIdx.x == 255) bsum[blockIdx.x] = v;
}

__global__ __launch_bounds__(256)
void scan2_kernel(const int* __restrict__ bsum, int* __restrict__ bscan, int nb)
{
    int i = threadIdx.x;
    int v = (i < nb) ? bsum[i] : 0;
    int lane = i & 63;
#pragma unroll
    for (int off = 1; off < 64; off <<= 1) {
        int u = __shfl_up(v, off);
        if (lane >= off) v += u;
    }
    __shared__ int wsum[4];
    if (lane == 63) wsum[i >> 6] = v;
    __syncthreads();
    int wid = i >> 6;
    int add = 0;
#pragma unroll
    for (int w = 0; w < 3; ++w) if (w < wid) add += wsum[w];
    v += add;
    bscan[i] = v;
}

__global__ __launch_bounds__(256)
void scan3_kernel(const int* __restrict__ deg, const int* __restrict__ incl,
                  const int* __restrict__ bscan, int* __restrict__ row_start,
                  int* __restrict__ cursor)
{
    int i = blockIdx.x * 256 + threadIdx.x;
    if (i >= NN) return;
    int b = blockIdx.x;
    int base = (b > 0) ? bscan[b - 1] : 0;
    int rs = base + incl[i] - deg[i];
    row_start[i] = rs;
    cursor[i] = rs;
    if (i == 0) row_start[NN] = NE;
}

__global__ __launch_bounds__(256)
void scatter_kernel(const int* __restrict__ ei, int* __restrict__ cursor,
                    int* __restrict__ srcs, int* __restrict__ eid)
{
    int e = blockIdx.x * 256 + threadIdx.x;
    if (e >= NE) return;
    int s = ei[e], d = ei[NE + e];
    int pos = atomicAdd(&cursor[d], 1);
    srcs[pos] = s;
    eid[pos] = e;
}

// --- permute edge_attr into dst-sorted order (one-time, reused 3 layers) ---
__global__ __launch_bounds__(256)
void permute_ea_kernel(const float* __restrict__ ea, const int* __restrict__ eid,
                       float* __restrict__ ea_s)
{
    int idx = blockIdx.x * 256 + threadIdx.x;
    if (idx >= NE * 7) return;
    int e = idx / 7, f2 = idx % 7;
    float2 v = *(const float2*)(ea + (size_t)eid[e] * EDGE_F + f2 * 2);
    *(float2*)(ea_s + (size_t)e * EDGE_F + f2 * 2) = v;
}

// ------ gather aggregation: zin[n] = h[n] + sum_{e->n} relu(h[src]+emb) ----
// one wave per node, 2 ch/lane; bf16 h gathers; unroll-4 load pipeline.
#define EMSG(HV, EP)                                                       \
    {                                                                      \
        float ax = bx, ay = by;                                            \
        _Pragma("unroll")                                                  \
        for (int f2 = 0; f2 < 7; ++f2) {                                   \
            float2 av = (EP)[f2];                                          \
            ax += av.x * w0[2 * f2] + av.y * w0[2 * f2 + 1];               \
            ay += av.x * w1[2 * f2] + av.y * w1[2 * f2 + 1];               \
        }                                                                  \
        float hx = __uint_as_float((HV) << 16);                            \
        float hy = __uint_as_float((HV) & 0xffff0000u);                    \
        accx += fmaxf(hx + ax, 0.f);                                       \
        accy += fmaxf(hy + ay, 0.f);                                       \
    }

__global__ __launch_bounds__(256)
void agg_kernel(const float* __restrict__ h, const uint* __restrict__ hb,
                const int* __restrict__ srcs, const int* __restrict__ row_start,
                const float* __restrict__ ea_s, const float* __restrict__ eW,
                const float* __restrict__ eb, float* __restrict__ zin)
{
    int node = blockIdx.x * 4 + (threadIdx.x >> 6);
    if (node >= NN) return;
    int lane = threadIdx.x & 63;
    int c2 = lane * 2;
    float w0[EDGE_F], w1[EDGE_F];
    {
        const float* p = eW + c2 * EDGE_F;
#pragma unroll
        for (int f = 0; f < EDGE_F; ++f) { w0[f] = p[f]; w1[f] = p[EDGE_F + f]; }
    }
    float bx = eb[c2], by = eb[c2 + 1];
    float accx = 0.f, accy = 0.f;
    int beg = __builtin_amdgcn_readfirstlane(row_start[node]);
    int end = __builtin_amdgcn_readfirstlane(row_start[node + 1]);
    int j = beg;
    for (; j + 4 <= end; j += 4) {
        int s0 = srcs[j], s1 = srcs[j + 1], s2 = srcs[j + 2], s3 = srcs[j + 3];
        uint hv0 = hb[(size_t)s0 * 64 + lane];
        uint hv1 = hb[(size_t)s1 * 64 + lane];
        uint hv2 = hb[(size_t)s2 * 64 + lane];
        uint hv3 = hb[(size_t)s3 * 64 + lane];
        const float2* e0 = (const float2*)(ea_s + (size_t)j * EDGE_F);
        const float2* e1 = e0 + 7;
        const float2* e2 = e0 + 14;
        const float2* e3 = e0 + 21;
        EMSG(hv0, e0); EMSG(hv1, e1); EMSG(hv2, e2); EMSG(hv3, e3);
    }
    for (; j < end; ++j) {
        int s0 = srcs[j];
        uint hv0 = hb[(size_t)s0 * 64 + lane];
        const float2* e0 = (const float2*)(ea_s + (size_t)j * EDGE_F);
        EMSG(hv0, e0);
    }
    float2 hn = *(const float2*)&h[(size_t)node * HD + c2];
    *(float2*)&zin[(size_t)node * HD + c2] = make_float2(hn.x + accx, hn.y + accy);
}

// --------------- dense layer GEMM: 64-node tile, 128x128 weight ------------
// MODE 0: out = relu(BN(a @ Wt + bias))            (lin1 + BN + relu)
// MODE 1: out = relu(a @ Wt + bias) + resid        (lin2 + relu + residual) + bf16 shadow
template <int MODE>
__global__ __launch_bounds__(256)
void gemm_kernel(const float* __restrict__ a, const float* __restrict__ Wt,
                 const float* __restrict__ bias,
                 const float* __restrict__ gamma, const float* __restrict__ beta,
                 const float* __restrict__ mean, const float* __restrict__ var,
                 const float* __restrict__ resid, float* __restrict__ out,
                 uint* __restrict__ hb, int n)
{
    __shared__ __align__(16) float in_lds[64][132];
    const int t = threadIdx.x;
    const int nb = blockIdx.x * 64;
    for (int idx = t; idx < 64 * HD; idx += 256) {
        int nn = idx >> 7, k = idx & 127;
        int gn = nb + nn;
        in_lds[nn][k] = (gn < n) ? a[(size_t)gn * HD + k] : 0.f;
    }
    __syncthreads();
    const int c0 = (t & 31) * 4;
    const int n0 = (t >> 5) * 8;
    float acc[8][4];
#pragma unroll
    for (int j = 0; j < 8; ++j)
#pragma unroll
        for (int c = 0; c < 4; ++c) acc[j][c] = 0.f;

    for (int k0 = 0; k0 < HD; k0 += 4) {
        float4 w0 = *(const float4*)&Wt[(k0 + 0) * HD + c0];
        float4 w1 = *(const float4*)&Wt[(k0 + 1) * HD + c0];
        float4 w2 = *(const float4*)&Wt[(k0 + 2) * HD + c0];
        float4 w3 = *(const float4*)&Wt[(k0 + 3) * HD + c0];
#pragma unroll
        for (int j = 0; j < 8; ++j) {
            float4 xv = *(const float4*)&in_lds[n0 + j][k0];
            acc[j][0] += xv.x * w0.x; acc[j][1] += xv.x * w0.y; acc[j][2] += xv.x * w0.z; acc[j][3] += xv.x * w0.w;
            acc[j][0] += xv.y * w1.x; acc[j][1] += xv.y * w1.y; acc[j][2] += xv.y * w1.z; acc[j][3] += xv.y * w1.w;
            acc[j][0] += xv.z * w2.x; acc[j][1] += xv.z * w2.y; acc[j][2] += xv.z * w2.z; acc[j][3] += xv.z * w2.w;
            acc[j][0] += xv.w * w3.x; acc[j][1] += xv.w * w3.y; acc[j][2] += xv.w * w3.z; acc[j][3] += xv.w * w3.w;
        }
    }
    float bi[4] = {bias[c0], bias[c0 + 1], bias[c0 + 2], bias[c0 + 3]};
    float sc[4], sh[4];
    if (MODE == 0) {
#pragma unroll
        for (int c = 0; c < 4; ++c) {
            float s = gamma[c0 + c] * rsqrtf(var[c0 + c] + BN_EPS);
            sc[c] = s;
            sh[c] = beta[c0 + c] - mean[c0 + c] * s;
        }
    }
#pragma unroll
    for (int j = 0; j < 8; ++j) {
        int gn = nb + n0 + j;
        if (gn < n) {
            float vals[4];
#pragma unroll
            for (int c = 0; c < 4; ++c) {
                float v = acc[j][c] + bi[c];
                if (MODE == 0) v = v * sc[c] + sh[c];
                v = fmaxf(v, 0.f);
                vals[c] = v;
            }
            if (MODE == 1) {
                float4 r = *(const float4*)&resid[(size_t)gn * HD + c0];
                vals[0] += r.x; vals[1] += r.y; vals[2] += r.z; vals[3] += r.w;
            }
            float4 o = {vals[0], vals[1], vals[2], vals[3]};
            *(float4*)&out[(size_t)gn * HD + c0] = o;
            if (MODE == 1) {
                uint u0 = bfround(vals[0]) | (bfround(vals[1]) << 16);
                uint u1 = bfround(vals[2]) | (bfround(vals[3]) << 16);
                *(uint2*)&hb[(size_t)gn * 64 + (c0 >> 1)] = make_uint2(u0, u1);
            }
        }
    }
}

// -------- pooling: sorted batch_idx -> chunked local sums, rare atomics ----
__global__ __launch_bounds__(128)
void pool_kernel(const float* __restrict__ h, const int* __restrict__ batch,
                 float* __restrict__ pooled, int* __restrict__ counts, int n, int chunk)
{
    int c = threadIdx.x;
    int n_start = blockIdx.x * chunk;
    if (n_start >= n) return;
    int n_end = min(n_start + chunk, n);
    float local = 0.f;
    int cnt = 0;
    int g_cur = batch[n_start];
    for (int nd = n_start; nd < n_end; ++nd) {
        int g = batch[nd];
        if (g != g_cur) {
            atomicAdd(&pooled[g_cur * HD + c], local);
            if (c == 0) atomicAdd(&counts[g_cur], cnt);
            local = 0.f; cnt = 0; g_cur = g;
        }
        local += h[(size_t)nd * HD + c];
        cnt++;
    }
    atomicAdd(&pooled[g_cur * HD + c], local);
    if (c == 0) atomicAdd(&counts[g_cur], cnt);
}

__global__ __launch_bounds__(128)
void final_kernel(const float* __restrict__ pooled, const int* __restrict__ counts,
                  const float* __restrict__ projT, const float* __restrict__ pb,
                  float* __restrict__ out)
{
    __shared__ float p_lds[HD];
    int g = blockIdx.x, p = threadIdx.x;
    float inv = 1.f / fmaxf((float)counts[g], 1.f);
    p_lds[p] = pooled[g * HD + p];
    __syncthreads();
    float acc = 0.f;
#pragma unroll 4
    for (int c = 0; c < HD; ++c) acc += p_lds[c] * projT[c * HD + p];
    out[g * HD + p] = acc * inv + pb[p];
}

extern "C" void kernel_launch(void* const* d_in, const int* in_sizes, int n_in,
                              void* d_out, int out_size, void* d_ws, size_t ws_size,
                              hipStream_t stream)
{
    const float* x        = (const float*)d_in[0];
    const int*   edge_idx = (const int*)d_in[1];
    const float* edge_attr= (const float*)d_in[2];
    const int*   batch    = (const int*)d_in[3];
    const float* node_W   = (const float*)d_in[4];
    const float* node_b   = (const float*)d_in[5];
    const float* edge_W   = (const float*)d_in[6];
    const float* edge_b   = (const float*)d_in[7];
    const float* lin1_W   = (const float*)d_in[8];
    const float* lin1_b   = (const float*)d_in[9];
    const float* bn_gamma = (const float*)d_in[10];
    const float* bn_beta  = (const float*)d_in[11];
    const float* bn_mean  = (const float*)d_in[12];
    const float* bn_var   = (const float*)d_in[13];
    const float* lin2_W   = (const float*)d_in[14];
    const float* lin2_b   = (const float*)d_in[15];
    const float* proj_b   = (const float*)d_in[17];

    char* ws = (char*)d_ws;
    float* h        = (float*)(ws);                   // 25.6 MB
    float* zin      = (float*)(ws + 25600000);        // 25.6 MB (in-place z)
    uint*  hb       = (uint*) (ws + 51200000);        // 12.8 MB bf16 shadow of h
    float* ea_s     = (float*)(ws + 64000000);        // 44.8 MB sorted edge_attr
    int*   srcs     = (int*)  (ws + 108800000);       // 3.2 MB
    int*   eid      = (int*)  (ws + 112000000);       // 3.2 MB
    float* wt       = (float*)(ws + 115200000);       // 458,752
    float* pooled   = (float*)(ws + 115658752);       // 32,768
    int*   counts   = (int*)  (ws + 115691520);       // 256
    int*   deg      = (int*)  (ws + 115691776);       // 200,000
    int*   incl     = (int*)  (ws + 115891776);       // 200,000
    int*   bsum     = (int*)  (ws + 116091776);       // 1,024
    int*   bscan    = (int*)  (ws + 116092800);       // 1,024
    int*   row_start= (int*)  (ws + 116093824);       // 200,064
    int*   cursor   = (int*)  (ws + 116293888);       // 200,000

    const int NB = (NN + 255) / 256;  // 196

    // --- CSR build + edge_attr permute (edge_index constant across layers) ---
    hipMemsetAsync(deg, 0, NN * sizeof(int), stream);
    hist_kernel<<<(NE + 255) / 256, 256, 0, stream>>>(edge_idx, deg);
    scan1_kernel<<<NB, 256, 0, stream>>>(deg, incl, bsum);
    scan2_kernel<<<1, 256, 0, stream>>>(bsum, bscan, NB);
    scan3_kernel<<<NB, 256, 0, stream>>>(deg, incl, bscan, row_start, cursor);
    scatter_kernel<<<(NE + 255) / 256, 256, 0, stream>>>(edge_idx, cursor, srcs, eid);
    permute_ea_kernel<<<(NE * 7 + 255) / 256, 256, 0, stream>>>(edge_attr, eid, ea_s);

    transpose_kernel<<<(7 * HD * HD + 255) / 256, 256, 0, stream>>>(
        lin1_W, lin2_W, (const float*)d_in[16], wt);
    node_embed_kernel<<<(NN * 64 + 255) / 256, 256, 0, stream>>>(x, node_W, node_b, h, hb, NN);

    for (int i = 0; i < NL; ++i) {
        agg_kernel<<<(NN + 3) / 4, 256, 0, stream>>>(
            h, hb, srcs, row_start, ea_s, edge_W, edge_b, zin);
        gemm_kernel<0><<<(NN + 63) / 64, 256, 0, stream>>>(
            zin, wt + i * HD * HD, lin1_b + i * HD,
            bn_gamma + i * HD, bn_beta + i * HD, bn_mean + i * HD, bn_var + i * HD,
            nullptr, zin, nullptr, NN);
        gemm_kernel<1><<<(NN + 63) / 64, 256, 0, stream>>>(
            zin, wt + (3 + i) * HD * HD, lin2_b + i * HD,
            nullptr, nullptr, nullptr, nullptr, h, h, hb, NN);
    }

    hipMemsetAsync(pooled, 0, NG * HD * sizeof(float), stream);
    hipMemsetAsync(counts, 0, NG * sizeof(int), stream);
    pool_kernel<<<NB, 128, 0, stream>>>(h, batch, pooled, counts, NN, 256);
    final_kernel<<<NG, HD, 0, stream>>>(pooled, counts, wt + 6 * HD * HD, proj_b, (float*)d_out);
}

// Round 4
// 501.527 us; speedup vs baseline: 4.8299x; 1.2672x over previous
//
#include <hip/hip_runtime.h>

typedef unsigned int uint;
typedef unsigned short ushort;
typedef __attribute__((ext_vector_type(8))) short bf16x8;
typedef __attribute__((ext_vector_type(4))) float f32x4;

#define NN 50000
#define NE 800000
#define NG 64
#define NODE_F 11
#define EDGE_F 14
#define HD 128
#define NL 3
#define BN_EPS 1e-5f

__device__ __forceinline__ uint bfround(float v) {
    uint b = __float_as_uint(v);
    return (b + 0x7fffu + ((b >> 16) & 1u)) >> 16;
}

// -------- node embedding: h = x @ node_W^T + node_b (+ bf16 shadow) --------
__global__ __launch_bounds__(256)
void node_embed_kernel(const float* __restrict__ x, const float* __restrict__ W,
                       const float* __restrict__ b, float* __restrict__ h,
                       uint* __restrict__ hb, int n)
{
    int idx = blockIdx.x * 256 + threadIdx.x;
    if (idx >= n * 64) return;
    int node = idx >> 6, cp = idx & 63;
    int c2 = cp * 2;
    const float* xr = x + node * NODE_F;
    const float* w0 = W + c2 * NODE_F;
    const float* w1 = w0 + NODE_F;
    float a0 = b[c2], a1 = b[c2 + 1];
#pragma unroll
    for (int f = 0; f < NODE_F; ++f) { float xv = xr[f]; a0 += xv * w0[f]; a1 += xv * w1[f]; }
    *(float2*)&h[(size_t)node * HD + c2] = make_float2(a0, a1);
    hb[idx] = bfround(a0) | (bfround(a1) << 16);
}

// ---- prep: lin1/lin2 -> bf16 wb[6][128][128] (row-major); proj -> projT f32
__global__ __launch_bounds__(256)
void prep_kernel(const float* __restrict__ lin1, const float* __restrict__ lin2,
                 const float* __restrict__ proj, ushort* __restrict__ wb,
                 float* __restrict__ projT)
{
    int idx = blockIdx.x * 256 + threadIdx.x;
    if (idx >= 7 * HD * HD) return;
    if (idx < 6 * HD * HD) {
        int m = idx >> 14, e = idx & (HD * HD - 1);
        const float* src = (m < 3) ? (lin1 + m * HD * HD) : (lin2 + (m - 3) * HD * HD);
        wb[idx] = (ushort)bfround(src[e]);
    } else {
        int e = idx - 6 * HD * HD;
        int r = e >> 7, c = e & 127;
        projT[c * HD + r] = proj[r * HD + c];
    }
}

// ----------------------------- CSR construction ----------------------------
__global__ __launch_bounds__(256)
void hist_kernel(const int* __restrict__ ei, int* __restrict__ deg)
{
    int e = blockIdx.x * 256 + threadIdx.x;
    if (e < NE) atomicAdd(&deg[ei[NE + e]], 1);
}

__global__ __launch_bounds__(256)
void scan1_kernel(const int* __restrict__ deg, int* __restrict__ incl, int* __restrict__ bsum)
{
    int i = blockIdx.x * 256 + threadIdx.x;
    int v = (i < NN) ? deg[i] : 0;
    int lane = threadIdx.x & 63;
#pragma unroll
    for (int off = 1; off < 64; off <<= 1) {
        int u = __shfl_up(v, off);
        if (lane >= off) v += u;
    }
    __shared__ int wsum[4];
    if (lane == 63) wsum[threadIdx.x >> 6] = v;
    __syncthreads();
    int wid = threadIdx.x >> 6;
    int add = 0;
#pragma unroll
    for (int w = 0; w < 3; ++w) if (w < wid) add += wsum[w];
    v += add;
    if (i < NN) incl[i] = v;
    if (threadIdx.x == 255) bsum[blockIdx.x] = v;
}

__global__ __launch_bounds__(256)
void scan2_kernel(const int* __restrict__ bsum, int* __restrict__ bscan, int nb)
{
    int i = threadIdx.x;
    int v = (i < nb) ? bsum[i] : 0;
    int lane = i & 63;
#pragma unroll
    for (int off = 1; off < 64; off <<= 1) {
        int u = __shfl_up(v, off);
        if (lane >= off) v += u;
    }
    __shared__ int wsum[4];
    if (lane == 63) wsum[i >> 6] = v;
    __syncthreads();
    int wid = i >> 6;
    int add = 0;
#pragma unroll
    for (int w = 0; w < 3; ++w) if (w < wid) add += wsum[w];
    v += add;
    bscan[i] = v;
}

__global__ __launch_bounds__(256)
void scan3_kernel(const int* __restrict__ deg, const int* __restrict__ incl,
                  const int* __restrict__ bscan, int* __restrict__ row_start,
                  int* __restrict__ cursor)
{
    int i = blockIdx.x * 256 + threadIdx.x;
    if (i >= NN) return;
    int b = blockIdx.x;
    int base = (b > 0) ? bscan[b - 1] : 0;
    int rs = base + incl[i] - deg[i];
    row_start[i] = rs;
    cursor[i] = rs;
    if (i == 0) row_start[NN] = NE;
}

__global__ __launch_bounds__(256)
void scatter_kernel(const int* __restrict__ ei, int* __restrict__ cursor,
                    int* __restrict__ srcs, int* __restrict__ eid)
{
    int e = blockIdx.x * 256 + threadIdx.x;
    if (e >= NE) return;
    int s = ei[e], d = ei[NE + e];
    int pos = atomicAdd(&cursor[d], 1);
    srcs[pos] = s;
    eid[pos] = e;
}

// --- permute edge_attr into dst-sorted order (one-time, reused 3 layers) ---
__global__ __launch_bounds__(256)
void permute_ea_kernel(const float* __restrict__ ea, const int* __restrict__ eid,
                       float* __restrict__ ea_s)
{
    int idx = blockIdx.x * 256 + threadIdx.x;
    if (idx >= NE * 7) return;
    int e = idx / 7, f2 = idx % 7;
    float2 v = *(const float2*)(ea + (size_t)eid[e] * EDGE_F + f2 * 2);
    *(float2*)(ea_s + (size_t)e * EDGE_F + f2 * 2) = v;
}

// ------ gather aggregation: zin[n] = h[n] + sum_{e->n} relu(h[src]+emb) ----
#define EMSG(HV, EP)                                                       \
    {                                                                      \
        float ax = bx, ay = by;                                            \
        _Pragma("unroll")                                                  \
        for (int f2 = 0; f2 < 7; ++f2) {                                   \
            float2 av = (EP)[f2];                                          \
            ax += av.x * w0[2 * f2] + av.y * w0[2 * f2 + 1];               \
            ay += av.x * w1[2 * f2] + av.y * w1[2 * f2 + 1];               \
        }                                                                  \
        float hx = __uint_as_float((HV) << 16);                            \
        float hy = __uint_as_float((HV) & 0xffff0000u);                    \
        accx += fmaxf(hx + ax, 0.f);                                       \
        accy += fmaxf(hy + ay, 0.f);                                       \
    }

__global__ __launch_bounds__(256)
void agg_kernel(const float* __restrict__ h, const uint* __restrict__ hb,
                const int* __restrict__ srcs, const int* __restrict__ row_start,
                const float* __restrict__ ea_s, const float* __restrict__ eW,
                const float* __restrict__ eb, float* __restrict__ zin)
{
    int node = blockIdx.x * 4 + (threadIdx.x >> 6);
    if (node >= NN) return;
    int lane = threadIdx.x & 63;
    int c2 = lane * 2;
    float w0[EDGE_F], w1[EDGE_F];
    {
        const float* p = eW + c2 * EDGE_F;
#pragma unroll
        for (int f = 0; f < EDGE_F; ++f) { w0[f] = p[f]; w1[f] = p[EDGE_F + f]; }
    }
    float bx = eb[c2], by = eb[c2 + 1];
    float accx = 0.f, accy = 0.f;
    int beg = __builtin_amdgcn_readfirstlane(row_start[node]);
    int end = __builtin_amdgcn_readfirstlane(row_start[node + 1]);
    int j = beg;
    for (; j + 4 <= end; j += 4) {
        int s0 = srcs[j], s1 = srcs[j + 1], s2 = srcs[j + 2], s3 = srcs[j + 3];
        uint hv0 = hb[(size_t)s0 * 64 + lane];
        uint hv1 = hb[(size_t)s1 * 64 + lane];
        uint hv2 = hb[(size_t)s2 * 64 + lane];
        uint hv3 = hb[(size_t)s3 * 64 + lane];
        const float2* e0 = (const float2*)(ea_s + (size_t)j * EDGE_F);
        const float2* e1 = e0 + 7;
        const float2* e2 = e0 + 14;
        const float2* e3 = e0 + 21;
        EMSG(hv0, e0); EMSG(hv1, e1); EMSG(hv2, e2); EMSG(hv3, e3);
    }
    for (; j < end; ++j) {
        int s0 = srcs[j];
        uint hv0 = hb[(size_t)s0 * 64 + lane];
        const float2* e0 = (const float2*)(ea_s + (size_t)j * EDGE_F);
        EMSG(hv0, e0);
    }
    float2 hn = *(const float2*)&h[(size_t)node * HD + c2];
    *(float2*)&zin[(size_t)node * HD + c2] = make_float2(hn.x + accx, hn.y + accy);
}

// ----------------- MFMA dense layer: 64 rows/block, 4 waves ----------------
// A (f32) split into bf16 hi+lo in LDS (XOR-swizzled); W bf16 from global.
// MODE 0: out = relu(BN(A @ W^T + bias))
// MODE 1: out = relu(A @ W^T + bias) + resid   (+ bf16 shadow hb)
template <int MODE>
__global__ __launch_bounds__(256)
void mfma_gemm_kernel(const float* __restrict__ a, const ushort* __restrict__ wb,
                      const float* __restrict__ bias,
                      const float* __restrict__ gamma, const float* __restrict__ beta,
                      const float* __restrict__ mean, const float* __restrict__ var,
                      const float* __restrict__ resid, float* __restrict__ out,
                      ushort* __restrict__ hb, int n)
{
    __shared__ uint Ahi[64 * 64];  // bf16[64][128], XOR-swizzled
    __shared__ uint Alo[64 * 64];
    const int t = threadIdx.x;
    const int nb = blockIdx.x * 64;

    // ---- stage A: each thread loads 32 floats of one row, split hi/lo ----
    {
        int row = t >> 2;
        int kq = (t & 3) * 32;
        int gn = nb + row;
        uint hiw[16], low[16];
        if (gn < n) {
            const float4* src = (const float4*)(a + (size_t)gn * HD + kq);
#pragma unroll
            for (int i = 0; i < 8; ++i) {
                float4 v = src[i];
                uint h0 = bfround(v.x), h1 = bfround(v.y), h2 = bfround(v.z), h3 = bfround(v.w);
                float r0 = v.x - __uint_as_float(h0 << 16);
                float r1 = v.y - __uint_as_float(h1 << 16);
                float r2 = v.z - __uint_as_float(h2 << 16);
                float r3 = v.w - __uint_as_float(h3 << 16);
                uint l0 = bfround(r0), l1 = bfround(r1), l2 = bfround(r2), l3 = bfround(r3);
                hiw[2 * i]     = h0 | (h1 << 16);
                hiw[2 * i + 1] = h2 | (h3 << 16);
                low[2 * i]     = l0 | (l1 << 16);
                low[2 * i + 1] = l2 | (l3 << 16);
            }
        } else {
#pragma unroll
            for (int i = 0; i < 16; ++i) { hiw[i] = 0; low[i] = 0; }
        }
        uint rowbase = row * 256;
#pragma unroll
        for (int i = 0; i < 4; ++i) {
            uint byte = (rowbase + (kq + 8 * i) * 2) ^ ((row & 7) << 4);
            *(uint4*)((char*)Ahi + byte) = make_uint4(hiw[4 * i], hiw[4 * i + 1], hiw[4 * i + 2], hiw[4 * i + 3]);
            *(uint4*)((char*)Alo + byte) = make_uint4(low[4 * i], low[4 * i + 1], low[4 * i + 2], low[4 * i + 3]);
        }
    }

    // ---- W fragments: wave w owns cols [32w, 32w+32) ----
    const int w  = t >> 6, l = t & 63;
    const int lc = l & 15, lk = l >> 4;
    bf16x8 wf[2][4];
#pragma unroll
    for (int ct = 0; ct < 2; ++ct)
#pragma unroll
        for (int ks = 0; ks < 4; ++ks)
            wf[ct][ks] = *(const bf16x8*)(wb + ((size_t)(w * 32 + ct * 16 + lc) * HD + ks * 32 + lk * 8));

    __syncthreads();

    f32x4 acc[4][2];
#pragma unroll
    for (int rt = 0; rt < 4; ++rt)
#pragma unroll
        for (int ct = 0; ct < 2; ++ct) acc[rt][ct] = (f32x4){0.f, 0.f, 0.f, 0.f};

#pragma unroll
    for (int ks = 0; ks < 4; ++ks) {
#pragma unroll
        for (int rt = 0; rt < 4; ++rt) {
            int row = rt * 16 + lc;
            uint byte = ((uint)(row * 256 + (ks * 32 + lk * 8) * 2)) ^ ((row & 7) << 4);
            bf16x8 ah = *(const bf16x8*)((char*)Ahi + byte);
            bf16x8 al = *(const bf16x8*)((char*)Alo + byte);
            acc[rt][0] = __builtin_amdgcn_mfma_f32_16x16x32_bf16(ah, wf[0][ks], acc[rt][0], 0, 0, 0);
            acc[rt][0] = __builtin_amdgcn_mfma_f32_16x16x32_bf16(al, wf[0][ks], acc[rt][0], 0, 0, 0);
            acc[rt][1] = __builtin_amdgcn_mfma_f32_16x16x32_bf16(ah, wf[1][ks], acc[rt][1], 0, 0, 0);
            acc[rt][1] = __builtin_amdgcn_mfma_f32_16x16x32_bf16(al, wf[1][ks], acc[rt][1], 0, 0, 0);
        }
    }

    // ---- epilogue ----
#pragma unroll
    for (int ct = 0; ct < 2; ++ct) {
        int col = w * 32 + ct * 16 + lc;
        float bi = bias[col];
        float scv = 0.f, shv = 0.f;
        if (MODE == 0) {
            scv = gamma[col] * rsqrtf(var[col] + BN_EPS);
            shv = beta[col] - mean[col] * scv;
        }
#pragma unroll
        for (int rt = 0; rt < 4; ++rt) {
#pragma unroll
            for (int r = 0; r < 4; ++r) {
                int row = nb + rt * 16 + lk * 4 + r;
                if (row < n) {
                    float v = acc[rt][ct][r] + bi;
                    if (MODE == 0) { v = v * scv + shv; v = fmaxf(v, 0.f); }
                    else           { v = fmaxf(v, 0.f) + resid[(size_t)row * HD + col]; }
                    out[(size_t)row * HD + col] = v;
                    if (MODE == 1) hb[(size_t)row * HD + col] = (ushort)bfround(v);
                }
            }
        }
    }
}

// -------- pooling: sorted batch_idx -> chunked local sums, rare atomics ----
__global__ __launch_bounds__(128)
void pool_kernel(const float* __restrict__ h, const int* __restrict__ batch,
                 float* __restrict__ pooled, int* __restrict__ counts, int n, int chunk)
{
    int c = threadIdx.x;
    int n_start = blockIdx.x * chunk;
    if (n_start >= n) return;
    int n_end = min(n_start + chunk, n);
    float local = 0.f;
    int cnt = 0;
    int g_cur = batch[n_start];
    for (int nd = n_start; nd < n_end; ++nd) {
        int g = batch[nd];
        if (g != g_cur) {
            atomicAdd(&pooled[g_cur * HD + c], local);
            if (c == 0) atomicAdd(&counts[g_cur], cnt);
            local = 0.f; cnt = 0; g_cur = g;
        }
        local += h[(size_t)nd * HD + c];
        cnt++;
    }
    atomicAdd(&pooled[g_cur * HD + c], local);
    if (c == 0) atomicAdd(&counts[g_cur], cnt);
}

__global__ __launch_bounds__(128)
void final_kernel(const float* __restrict__ pooled, const int* __restrict__ counts,
                  const float* __restrict__ projT, const float* __restrict__ pb,
                  float* __restrict__ out)
{
    __shared__ float p_lds[HD];
    int g = blockIdx.x, p = threadIdx.x;
    float inv = 1.f / fmaxf((float)counts[g], 1.f);
    p_lds[p] = pooled[g * HD + p];
    __syncthreads();
    float acc = 0.f;
#pragma unroll 4
    for (int c = 0; c < HD; ++c) acc += p_lds[c] * projT[c * HD + p];
    out[g * HD + p] = acc * inv + pb[p];
}

extern "C" void kernel_launch(void* const* d_in, const int* in_sizes, int n_in,
                              void* d_out, int out_size, void* d_ws, size_t ws_size,
                              hipStream_t stream)
{
    const float* x        = (const float*)d_in[0];
    const int*   edge_idx = (const int*)d_in[1];
    const float* edge_attr= (const float*)d_in[2];
    const int*   batch    = (const int*)d_in[3];
    const float* node_W   = (const float*)d_in[4];
    const float* node_b   = (const float*)d_in[5];
    const float* edge_W   = (const float*)d_in[6];
    const float* edge_b   = (const float*)d_in[7];
    const float* lin1_W   = (const float*)d_in[8];
    const float* lin1_b   = (const float*)d_in[9];
    const float* bn_gamma = (const float*)d_in[10];
    const float* bn_beta  = (const float*)d_in[11];
    const float* bn_mean  = (const float*)d_in[12];
    const float* bn_var   = (const float*)d_in[13];
    const float* lin2_W   = (const float*)d_in[14];
    const float* lin2_b   = (const float*)d_in[15];
    const float* proj_b   = (const float*)d_in[17];

    char* ws = (char*)d_ws;
    float*  h        = (float*) (ws);                   // 25.6 MB
    float*  zin      = (float*) (ws + 25600000);        // 25.6 MB (in-place z)
    uint*   hb       = (uint*)  (ws + 51200000);        // 12.8 MB bf16 shadow (ushort/channel)
    float*  ea_s     = (float*) (ws + 64000000);        // 44.8 MB sorted edge_attr
    int*    srcs     = (int*)   (ws + 108800000);       // 3.2 MB
    int*    eid      = (int*)   (ws + 112000000);       // 3.2 MB
    ushort* wb       = (ushort*)(ws + 115200000);       // 196,608 (6 bf16 mats)
    float*  projT    = (float*) (ws + 115400000);       // 65,536
    float*  pooled   = (float*) (ws + 115466240);       // 32,768
    int*    counts   = (int*)   (ws + 115499008);       // 256
    int*    deg      = (int*)   (ws + 115499264);       // 200,000
    int*    incl     = (int*)   (ws + 115699264);       // 200,000
    int*    bsum     = (int*)   (ws + 115899264);       // 1,024
    int*    bscan    = (int*)   (ws + 115900288);       // 1,024
    int*    row_start= (int*)   (ws + 115901312);       // 200,064
    int*    cursor   = (int*)   (ws + 116101376);       // 200,000

    const int NB = (NN + 255) / 256;  // 196

    // --- CSR build + edge_attr permute (edge_index constant across layers) ---
    hipMemsetAsync(deg, 0, NN * sizeof(int), stream);
    hist_kernel<<<(NE + 255) / 256, 256, 0, stream>>>(edge_idx, deg);
    scan1_kernel<<<NB, 256, 0, stream>>>(deg, incl, bsum);
    scan2_kernel<<<1, 256, 0, stream>>>(bsum, bscan, NB);
    scan3_kernel<<<NB, 256, 0, stream>>>(deg, incl, bscan, row_start, cursor);
    scatter_kernel<<<(NE + 255) / 256, 256, 0, stream>>>(edge_idx, cursor, srcs, eid);
    permute_ea_kernel<<<(NE * 7 + 255) / 256, 256, 0, stream>>>(edge_attr, eid, ea_s);

    prep_kernel<<<(7 * HD * HD + 255) / 256, 256, 0, stream>>>(
        lin1_W, lin2_W, (const float*)d_in[16], wb, projT);
    node_embed_kernel<<<(NN * 64 + 255) / 256, 256, 0, stream>>>(x, node_W, node_b, h, hb, NN);

    for (int i = 0; i < NL; ++i) {
        agg_kernel<<<(NN + 3) / 4, 256, 0, stream>>>(
            h, hb, srcs, row_start, ea_s, edge_W, edge_b, zin);
        mfma_gemm_kernel<0><<<(NN + 63) / 64, 256, 0, stream>>>(
            zin, wb + (size_t)i * HD * HD, lin1_b + i * HD,
            bn_gamma + i * HD, bn_beta + i * HD, bn_mean + i * HD, bn_var + i * HD,
            nullptr, zin, nullptr, NN);
        mfma_gemm_kernel<1><<<(NN + 63) / 64, 256, 0, stream>>>(
            zin, wb + (size_t)(3 + i) * HD * HD, lin2_b + i * HD,
            nullptr, nullptr, nullptr, nullptr, h, h, (ushort*)hb, NN);
    }

    hipMemsetAsync(pooled, 0, NG * HD * sizeof(float), stream);
    hipMemsetAsync(counts, 0, NG * sizeof(int), stream);
    pool_kernel<<<(NN + 31) / 32, 128, 0, stream>>>(h, batch, pooled, counts, NN, 32);
    final_kernel<<<NG, HD, 0, stream>>>(pooled, counts, projT, proj_b, (float*)d_out);
}

// Round 5
// 488.009 us; speedup vs baseline: 4.9637x; 1.0277x over previous
//
#include <hip/hip_runtime.h>

typedef unsigned int uint;
typedef unsigned short ushort;
typedef __attribute__((ext_vector_type(8))) short bf16x8;
typedef __attribute__((ext_vector_type(4))) float f32x4;

#define NN 50000
#define NE 800000
#define NG 64
#define NODE_F 11
#define EDGE_F 14
#define HD 128
#define NL 3
#define BN_EPS 1e-5f

__device__ __forceinline__ uint bfround(float v) {
    uint b = __float_as_uint(v);
    return (b + 0x7fffu + ((b >> 16) & 1u)) >> 16;
}

// -------- node embedding: h = x @ node_W^T + node_b (+ bf16 shadow) --------
__global__ __launch_bounds__(256)
void node_embed_kernel(const float* __restrict__ x, const float* __restrict__ W,
                       const float* __restrict__ b, float* __restrict__ h,
                       uint* __restrict__ hb, int n)
{
    int idx = blockIdx.x * 256 + threadIdx.x;
    if (idx >= n * 64) return;
    int node = idx >> 6, cp = idx & 63;
    int c2 = cp * 2;
    const float* xr = x + node * NODE_F;
    const float* w0 = W + c2 * NODE_F;
    const float* w1 = w0 + NODE_F;
    float a0 = b[c2], a1 = b[c2 + 1];
#pragma unroll
    for (int f = 0; f < NODE_F; ++f) { float xv = xr[f]; a0 += xv * w0[f]; a1 += xv * w1[f]; }
    *(float2*)&h[(size_t)node * HD + c2] = make_float2(a0, a1);
    hb[idx] = bfround(a0) | (bfround(a1) << 16);
}

// ---- prep: lin1/lin2 -> bf16 wb[6][128][128] (row-major); proj -> projT f32
__global__ __launch_bounds__(256)
void prep_kernel(const float* __restrict__ lin1, const float* __restrict__ lin2,
                 const float* __restrict__ proj, ushort* __restrict__ wb,
                 float* __restrict__ projT)
{
    int idx = blockIdx.x * 256 + threadIdx.x;
    if (idx >= 7 * HD * HD) return;
    if (idx < 6 * HD * HD) {
        int m = idx >> 14, e = idx & (HD * HD - 1);
        const float* src = (m < 3) ? (lin1 + m * HD * HD) : (lin2 + (m - 3) * HD * HD);
        wb[idx] = (ushort)bfround(src[e]);
    } else {
        int e = idx - 6 * HD * HD;
        int r = e >> 7, c = e & 127;
        projT[c * HD + r] = proj[r * HD + c];
    }
}

// ----------------------------- CSR construction ----------------------------
__global__ __launch_bounds__(256)
void hist_kernel(const int* __restrict__ ei, int* __restrict__ deg)
{
    int e = blockIdx.x * 256 + threadIdx.x;
    if (e < NE) atomicAdd(&deg[ei[NE + e]], 1);
}

__global__ __launch_bounds__(256)
void scan1_kernel(const int* __restrict__ deg, int* __restrict__ incl, int* __restrict__ bsum)
{
    int i = blockIdx.x * 256 + threadIdx.x;
    int v = (i < NN) ? deg[i] : 0;
    int lane = threadIdx.x & 63;
#pragma unroll
    for (int off = 1; off < 64; off <<= 1) {
        int u = __shfl_up(v, off);
        if (lane >= off) v += u;
    }
    __shared__ int wsum[4];
    if (lane == 63) wsum[threadIdx.x >> 6] = v;
    __syncthreads();
    int wid = threadIdx.x >> 6;
    int add = 0;
#pragma unroll
    for (int w = 0; w < 3; ++w) if (w < wid) add += wsum[w];
    v += add;
    if (i < NN) incl[i] = v;
    if (threadIdx.x == 255) bsum[blockIdx.x] = v;
}

__global__ __launch_bounds__(256)
void scan2_kernel(const int* __restrict__ bsum, int* __restrict__ bscan, int nb)
{
    int i = threadIdx.x;
    int v = (i < nb) ? bsum[i] : 0;
    int lane = i & 63;
#pragma unroll
    for (int off = 1; off < 64; off <<= 1) {
        int u = __shfl_up(v, off);
        if (lane >= off) v += u;
    }
    __shared__ int wsum[4];
    if (lane == 63) wsum[i >> 6] = v;
    __syncthreads();
    int wid = i >> 6;
    int add = 0;
#pragma unroll
    for (int w = 0; w < 3; ++w) if (w < wid) add += wsum[w];
    v += add;
    bscan[i] = v;
}

__global__ __launch_bounds__(256)
void scan3_kernel(const int* __restrict__ deg, const int* __restrict__ incl,
                  const int* __restrict__ bscan, int* __restrict__ row_start,
                  int* __restrict__ cursor)
{
    int i = blockIdx.x * 256 + threadIdx.x;
    if (i >= NN) return;
    int b = blockIdx.x;
    int base = (b > 0) ? bscan[b - 1] : 0;
    int rs = base + incl[i] - deg[i];
    row_start[i] = rs;
    cursor[i] = rs;
    if (i == 0) row_start[NN] = NE;
}

__global__ __launch_bounds__(256)
void scatter_kernel(const int* __restrict__ ei, int* __restrict__ cursor,
                    int* __restrict__ srcs, int* __restrict__ eid)
{
    int e = blockIdx.x * 256 + threadIdx.x;
    if (e >= NE) return;
    int s = ei[e], d = ei[NE + e];
    int pos = atomicAdd(&cursor[d], 1);
    srcs[pos] = s;
    eid[pos] = e;
}

// ---- one-time: emb[j] = bf16(edge_attr[eid[j]] @ eW^T + eb), dst-sorted ----
__global__ __launch_bounds__(256)
void embed_edges_kernel(const float* __restrict__ ea, const int* __restrict__ eid,
                        const float* __restrict__ eW, const float* __restrict__ eb,
                        uint* __restrict__ emb)
{
    const int EC = 64;
    int wv = blockIdx.x * 4 + (threadIdx.x >> 6);
    int j0 = wv * EC;
    if (j0 >= NE) return;
    int lane = threadIdx.x & 63;
    int c2 = lane * 2;
    float w0[EDGE_F], w1[EDGE_F];
    {
        const float* p = eW + c2 * EDGE_F;
#pragma unroll
        for (int f = 0; f < EDGE_F; ++f) { w0[f] = p[f]; w1[f] = p[EDGE_F + f]; }
    }
    float bx = eb[c2], by = eb[c2 + 1];
    int jend = min(j0 + EC, NE);
    for (int j = j0; j < jend; ++j) {
        int e = __builtin_amdgcn_readfirstlane(eid[j]);
        const float2* er = (const float2*)(ea + (size_t)e * EDGE_F);
        float ax = bx, ay = by;
#pragma unroll
        for (int f2 = 0; f2 < 7; ++f2) {
            float2 av = er[f2];
            ax += av.x * w0[2 * f2] + av.y * w0[2 * f2 + 1];
            ay += av.x * w1[2 * f2] + av.y * w1[2 * f2 + 1];
        }
        emb[(size_t)j * 64 + lane] = bfround(ax) | (bfround(ay) << 16);
    }
}

// ------ agg (emb path): zin[n] = h[n] + sum_j relu(hb[src_j] + emb[j]) -----
#define MSG2(HV, EV)                                                        \
    {                                                                       \
        float hx = __uint_as_float((HV) << 16);                             \
        float hy = __uint_as_float((HV) & 0xffff0000u);                     \
        float ex = __uint_as_float((EV) << 16);                             \
        float ey = __uint_as_float((EV) & 0xffff0000u);                     \
        accx += fmaxf(hx + ex, 0.f);                                        \
        accy += fmaxf(hy + ey, 0.f);                                        \
    }

__global__ __launch_bounds__(256)
void agg_emb_kernel(const float* __restrict__ h, const uint* __restrict__ hb,
                    const int* __restrict__ srcs, const int* __restrict__ row_start,
                    const uint* __restrict__ emb, float* __restrict__ zin)
{
    int node = blockIdx.x * 4 + (threadIdx.x >> 6);
    if (node >= NN) return;
    int lane = threadIdx.x & 63;
    int c2 = lane * 2;
    float accx = 0.f, accy = 0.f;
    int beg = __builtin_amdgcn_readfirstlane(row_start[node]);
    int end = __builtin_amdgcn_readfirstlane(row_start[node + 1]);
    int j = beg;
    for (; j + 4 <= end; j += 4) {
        int s0 = srcs[j], s1 = srcs[j + 1], s2 = srcs[j + 2], s3 = srcs[j + 3];
        uint hv0 = hb[(size_t)s0 * 64 + lane];
        uint hv1 = hb[(size_t)s1 * 64 + lane];
        uint hv2 = hb[(size_t)s2 * 64 + lane];
        uint hv3 = hb[(size_t)s3 * 64 + lane];
        uint ev0 = emb[(size_t)j * 64 + lane];
        uint ev1 = emb[(size_t)(j + 1) * 64 + lane];
        uint ev2 = emb[(size_t)(j + 2) * 64 + lane];
        uint ev3 = emb[(size_t)(j + 3) * 64 + lane];
        MSG2(hv0, ev0); MSG2(hv1, ev1); MSG2(hv2, ev2); MSG2(hv3, ev3);
    }
    for (; j < end; ++j) {
        uint hv0 = hb[(size_t)srcs[j] * 64 + lane];
        uint ev0 = emb[(size_t)j * 64 + lane];
        MSG2(hv0, ev0);
    }
    float2 hn = *(const float2*)&h[(size_t)node * HD + c2];
    *(float2*)&zin[(size_t)node * HD + c2] = make_float2(hn.x + accx, hn.y + accy);
}

// ------ agg (fallback, recompute): as round 4, reads dst-sorted ea_s f32 ----
#define EMSG(HV, EP)                                                       \
    {                                                                      \
        float ax = bx, ay = by;                                            \
        _Pragma("unroll")                                                  \
        for (int f2 = 0; f2 < 7; ++f2) {                                   \
            float2 av = (EP)[f2];                                          \
            ax += av.x * w0[2 * f2] + av.y * w0[2 * f2 + 1];               \
            ay += av.x * w1[2 * f2] + av.y * w1[2 * f2 + 1];               \
        }                                                                  \
        float hx = __uint_as_float((HV) << 16);                            \
        float hy = __uint_as_float((HV) & 0xffff0000u);                    \
        accx += fmaxf(hx + ax, 0.f);                                       \
        accy += fmaxf(hy + ay, 0.f);                                       \
    }

__global__ __launch_bounds__(256)
void permute_ea_kernel(const float* __restrict__ ea, const int* __restrict__ eid,
                       float* __restrict__ ea_s)
{
    int idx = blockIdx.x * 256 + threadIdx.x;
    if (idx >= NE * 7) return;
    int e = idx / 7, f2 = idx % 7;
    float2 v = *(const float2*)(ea + (size_t)eid[e] * EDGE_F + f2 * 2);
    *(float2*)(ea_s + (size_t)e * EDGE_F + f2 * 2) = v;
}

__global__ __launch_bounds__(256)
void agg_recompute_kernel(const float* __restrict__ h, const uint* __restrict__ hb,
                          const int* __restrict__ srcs, const int* __restrict__ row_start,
                          const float* __restrict__ ea_s, const float* __restrict__ eW,
                          const float* __restrict__ eb, float* __restrict__ zin)
{
    int node = blockIdx.x * 4 + (threadIdx.x >> 6);
    if (node >= NN) return;
    int lane = threadIdx.x & 63;
    int c2 = lane * 2;
    float w0[EDGE_F], w1[EDGE_F];
    {
        const float* p = eW + c2 * EDGE_F;
#pragma unroll
        for (int f = 0; f < EDGE_F; ++f) { w0[f] = p[f]; w1[f] = p[EDGE_F + f]; }
    }
    float bx = eb[c2], by = eb[c2 + 1];
    float accx = 0.f, accy = 0.f;
    int beg = __builtin_amdgcn_readfirstlane(row_start[node]);
    int end = __builtin_amdgcn_readfirstlane(row_start[node + 1]);
    int j = beg;
    for (; j + 4 <= end; j += 4) {
        int s0 = srcs[j], s1 = srcs[j + 1], s2 = srcs[j + 2], s3 = srcs[j + 3];
        uint hv0 = hb[(size_t)s0 * 64 + lane];
        uint hv1 = hb[(size_t)s1 * 64 + lane];
        uint hv2 = hb[(size_t)s2 * 64 + lane];
        uint hv3 = hb[(size_t)s3 * 64 + lane];
        const float2* e0 = (const float2*)(ea_s + (size_t)j * EDGE_F);
        const float2* e1 = e0 + 7;
        const float2* e2 = e0 + 14;
        const float2* e3 = e0 + 21;
        EMSG(hv0, e0); EMSG(hv1, e1); EMSG(hv2, e2); EMSG(hv3, e3);
    }
    for (; j < end; ++j) {
        uint hv0 = hb[(size_t)srcs[j] * 64 + lane];
        const float2* e0 = (const float2*)(ea_s + (size_t)j * EDGE_F);
        EMSG(hv0, e0);
    }
    float2 hn = *(const float2*)&h[(size_t)node * HD + c2];
    *(float2*)&zin[(size_t)node * HD + c2] = make_float2(hn.x + accx, hn.y + accy);
}

// --------- fused layer: h = relu(relu(BN(zin@W1^T+b1))@W2^T+b2) + h --------
// 64 rows/block, 4 waves. zin staged hi/lo bf16 (swizzled); z single bf16.
__global__ __launch_bounds__(256)
void fused_layer_kernel(const float* __restrict__ zin,
                        const ushort* __restrict__ w1b, const float* __restrict__ b1,
                        const float* __restrict__ gamma, const float* __restrict__ beta,
                        const float* __restrict__ mean, const float* __restrict__ var,
                        const ushort* __restrict__ w2b, const float* __restrict__ b2,
                        float* __restrict__ h, ushort* __restrict__ hb, int n)
{
    __shared__ uint Ahi[64 * 64];  // bf16[64][128], XOR-swizzled; reused for z
    __shared__ uint Alo[64 * 64];
    const int t = threadIdx.x;
    const int nb = blockIdx.x * 64;

    // ---- stage zin: 32 floats/thread, split bf16 hi/lo ----
    {
        int row = t >> 2;
        int kq = (t & 3) * 32;
        int gn = nb + row;
        uint hiw[16], low[16];
        if (gn < n) {
            const float4* src = (const float4*)(zin + (size_t)gn * HD + kq);
#pragma unroll
            for (int i = 0; i < 8; ++i) {
                float4 v = src[i];
                uint h0 = bfround(v.x), h1 = bfround(v.y), h2 = bfround(v.z), h3 = bfround(v.w);
                float r0 = v.x - __uint_as_float(h0 << 16);
                float r1 = v.y - __uint_as_float(h1 << 16);
                float r2 = v.z - __uint_as_float(h2 << 16);
                float r3 = v.w - __uint_as_float(h3 << 16);
                hiw[2 * i]     = h0 | (h1 << 16);
                hiw[2 * i + 1] = h2 | (h3 << 16);
                low[2 * i]     = bfround(r0) | (bfround(r1) << 16);
                low[2 * i + 1] = bfround(r2) | (bfround(r3) << 16);
            }
        } else {
#pragma unroll
            for (int i = 0; i < 16; ++i) { hiw[i] = 0; low[i] = 0; }
        }
        uint rowbase = row * 256;
#pragma unroll
        for (int i = 0; i < 4; ++i) {
            uint byte = (rowbase + (kq + 8 * i) * 2) ^ ((row & 7) << 4);
            *(uint4*)((char*)Ahi + byte) = make_uint4(hiw[4 * i], hiw[4 * i + 1], hiw[4 * i + 2], hiw[4 * i + 3]);
            *(uint4*)((char*)Alo + byte) = make_uint4(low[4 * i], low[4 * i + 1], low[4 * i + 2], low[4 * i + 3]);
        }
    }

    const int w  = t >> 6, l = t & 63;
    const int lc = l & 15, lk = l >> 4;
    bf16x8 wf1[2][4], wf2[2][4];
#pragma unroll
    for (int ct = 0; ct < 2; ++ct)
#pragma unroll
        for (int ks = 0; ks < 4; ++ks) {
            size_t off = (size_t)(w * 32 + ct * 16 + lc) * HD + ks * 32 + lk * 8;
            wf1[ct][ks] = *(const bf16x8*)(w1b + off);
            wf2[ct][ks] = *(const bf16x8*)(w2b + off);
        }

    __syncthreads();

    // ---- GEMM1: hi/lo ----
    f32x4 acc[4][2];
#pragma unroll
    for (int rt = 0; rt < 4; ++rt)
#pragma unroll
        for (int ct = 0; ct < 2; ++ct) acc[rt][ct] = (f32x4){0.f, 0.f, 0.f, 0.f};

#pragma unroll
    for (int ks = 0; ks < 4; ++ks) {
#pragma unroll
        for (int rt = 0; rt < 4; ++rt) {
            int row = rt * 16 + lc;
            uint byte = ((uint)(row * 256 + (ks * 32 + lk * 8) * 2)) ^ ((row & 7) << 4);
            bf16x8 ah = *(const bf16x8*)((char*)Ahi + byte);
            bf16x8 al = *(const bf16x8*)((char*)Alo + byte);
            acc[rt][0] = __builtin_amdgcn_mfma_f32_16x16x32_bf16(ah, wf1[0][ks], acc[rt][0], 0, 0, 0);
            acc[rt][0] = __builtin_amdgcn_mfma_f32_16x16x32_bf16(al, wf1[0][ks], acc[rt][0], 0, 0, 0);
            acc[rt][1] = __builtin_amdgcn_mfma_f32_16x16x32_bf16(ah, wf1[1][ks], acc[rt][1], 0, 0, 0);
            acc[rt][1] = __builtin_amdgcn_mfma_f32_16x16x32_bf16(al, wf1[1][ks], acc[rt][1], 0, 0, 0);
        }
    }

    __syncthreads();  // all GEMM1 LDS reads done before overwrite

    // ---- epilogue1: BN + relu -> z (bf16) into Ahi ----
#pragma unroll
    for (int ct = 0; ct < 2; ++ct) {
        int col = w * 32 + ct * 16 + lc;
        float bi = b1[col];
        float scv = gamma[col] * rsqrtf(var[col] + BN_EPS);
        float shv = beta[col] - mean[col] * scv;
#pragma unroll
        for (int rt = 0; rt < 4; ++rt) {
#pragma unroll
            for (int r = 0; r < 4; ++r) {
                int rowl = rt * 16 + lk * 4 + r;
                float v = (acc[rt][ct][r] + bi) * scv + shv;
                v = fmaxf(v, 0.f);
                uint byte = ((uint)(rowl * 256 + col * 2)) ^ ((rowl & 7) << 4);
                *(ushort*)((char*)Ahi + byte) = (ushort)bfround(v);
            }
        }
    }

    __syncthreads();

    // ---- GEMM2: single bf16 ----
    f32x4 acc2[4][2];
#pragma unroll
    for (int rt = 0; rt < 4; ++rt)
#pragma unroll
        for (int ct = 0; ct < 2; ++ct) acc2[rt][ct] = (f32x4){0.f, 0.f, 0.f, 0.f};

#pragma unroll
    for (int ks = 0; ks < 4; ++ks) {
#pragma unroll
        for (int rt = 0; rt < 4; ++rt) {
            int row = rt * 16 + lc;
            uint byte = ((uint)(row * 256 + (ks * 32 + lk * 8) * 2)) ^ ((row & 7) << 4);
            bf16x8 az = *(const bf16x8*)((char*)Ahi + byte);
            acc2[rt][0] = __builtin_amdgcn_mfma_f32_16x16x32_bf16(az, wf2[0][ks], acc2[rt][0], 0, 0, 0);
            acc2[rt][1] = __builtin_amdgcn_mfma_f32_16x16x32_bf16(az, wf2[1][ks], acc2[rt][1], 0, 0, 0);
        }
    }

    // ---- epilogue2: relu + residual; write h (f32) + hb (bf16) ----
#pragma unroll
    for (int ct = 0; ct < 2; ++ct) {
        int col = w * 32 + ct * 16 + lc;
        float bi = b2[col];
#pragma unroll
        for (int rt = 0; rt < 4; ++rt) {
#pragma unroll
            for (int r = 0; r < 4; ++r) {
                int row = nb + rt * 16 + lk * 4 + r;
                if (row < n) {
                    float v = fmaxf(acc2[rt][ct][r] + bi, 0.f) + h[(size_t)row * HD + col];
                    h[(size_t)row * HD + col] = v;
                    hb[(size_t)row * HD + col] = (ushort)bfround(v);
                }
            }
        }
    }
}

// -------- pooling: sorted batch_idx -> chunked local sums, rare atomics ----
__global__ __launch_bounds__(128)
void pool_kernel(const float* __restrict__ h, const int* __restrict__ batch,
                 float* __restrict__ pooled, int* __restrict__ counts, int n, int chunk)
{
    int c = threadIdx.x;
    int n_start = blockIdx.x * chunk;
    if (n_start >= n) return;
    int n_end = min(n_start + chunk, n);
    float local = 0.f;
    int cnt = 0;
    int g_cur = batch[n_start];
    for (int nd = n_start; nd < n_end; ++nd) {
        int g = batch[nd];
        if (g != g_cur) {
            atomicAdd(&pooled[g_cur * HD + c], local);
            if (c == 0) atomicAdd(&counts[g_cur], cnt);
            local = 0.f; cnt = 0; g_cur = g;
        }
        local += h[(size_t)nd * HD + c];
        cnt++;
    }
    atomicAdd(&pooled[g_cur * HD + c], local);
    if (c == 0) atomicAdd(&counts[g_cur], cnt);
}

__global__ __launch_bounds__(128)
void final_kernel(const float* __restrict__ pooled, const int* __restrict__ counts,
                  const float* __restrict__ projT, const float* __restrict__ pb,
                  float* __restrict__ out)
{
    __shared__ float p_lds[HD];
    int g = blockIdx.x, p = threadIdx.x;
    float inv = 1.f / fmaxf((float)counts[g], 1.f);
    p_lds[p] = pooled[g * HD + p];
    __syncthreads();
    float acc = 0.f;
#pragma unroll 4
    for (int c = 0; c < HD; ++c) acc += p_lds[c] * projT[c * HD + p];
    out[g * HD + p] = acc * inv + pb[p];
}

extern "C" void kernel_launch(void* const* d_in, const int* in_sizes, int n_in,
                              void* d_out, int out_size, void* d_ws, size_t ws_size,
                              hipStream_t stream)
{
    const float* x        = (const float*)d_in[0];
    const int*   edge_idx = (const int*)d_in[1];
    const float* edge_attr= (const float*)d_in[2];
    const int*   batch    = (const int*)d_in[3];
    const float* node_W   = (const float*)d_in[4];
    const float* node_b   = (const float*)d_in[5];
    const float* edge_W   = (const float*)d_in[6];
    const float* edge_b   = (const float*)d_in[7];
    const float* lin1_W   = (const float*)d_in[8];
    const float* lin1_b   = (const float*)d_in[9];
    const float* bn_gamma = (const float*)d_in[10];
    const float* bn_beta  = (const float*)d_in[11];
    const float* bn_mean  = (const float*)d_in[12];
    const float* bn_var   = (const float*)d_in[13];
    const float* lin2_W   = (const float*)d_in[14];
    const float* lin2_b   = (const float*)d_in[15];
    const float* proj_b   = (const float*)d_in[17];

    char* ws = (char*)d_ws;
    float*  h        = (float*) (ws);                  // 25.6 MB
    float*  zin      = (float*) (ws + 25600000);       // 25.6 MB
    uint*   hb       = (uint*)  (ws + 51200000);       // 12.8 MB (packed bf16, 2ch/uint)
    int*    srcs     = (int*)   (ws + 64000000);       // 3.2 MB
    int*    eid      = (int*)   (ws + 67200000);       // 3.2 MB
    ushort* wb       = (ushort*)(ws + 70400000);       // 196,608
    float*  projT    = (float*) (ws + 70700000);       // 65,536
    float*  pooled   = (float*) (ws + 70800000);       // 32,768
    int*    counts   = (int*)   (ws + 70840000);       // 256
    int*    deg      = (int*)   (ws + 70900000);       // 200,000
    int*    incl     = (int*)   (ws + 71100000);       // 200,000
    int*    bsum     = (int*)   (ws + 71300000);       // 1,024
    int*    bscan    = (int*)   (ws + 71310000);       // 1,024
    int*    row_start= (int*)   (ws + 71320000);       // 200,064
    int*    cursor   = (int*)   (ws + 71530000);       // 200,000
    // path-specific region at 72 MB:
    uint*   emb      = (uint*)  (ws + 72000000);       // 204.8 MB (emb path)
    float*  ea_s     = (float*) (ws + 72000000);       // 44.8 MB (fallback path)
    const bool use_emb = (ws_size >= (size_t)277000000);

    const int NB = (NN + 255) / 256;  // 196

    // --- CSR build (edge_index constant across layers) ---
    hipMemsetAsync(deg, 0, NN * sizeof(int), stream);
    hist_kernel<<<(NE + 255) / 256, 256, 0, stream>>>(edge_idx, deg);
    scan1_kernel<<<NB, 256, 0, stream>>>(deg, incl, bsum);
    scan2_kernel<<<1, 256, 0, stream>>>(bsum, bscan, NB);
    scan3_kernel<<<NB, 256, 0, stream>>>(deg, incl, bscan, row_start, cursor);
    scatter_kernel<<<(NE + 255) / 256, 256, 0, stream>>>(edge_idx, cursor, srcs, eid);

    if (use_emb) {
        embed_edges_kernel<<<(NE / 64 + 3) / 4, 256, 0, stream>>>(
            edge_attr, eid, edge_W, edge_b, emb);
    } else {
        permute_ea_kernel<<<(NE * 7 + 255) / 256, 256, 0, stream>>>(edge_attr, eid, ea_s);
    }

    prep_kernel<<<(7 * HD * HD + 255) / 256, 256, 0, stream>>>(
        lin1_W, lin2_W, (const float*)d_in[16], wb, projT);
    node_embed_kernel<<<(NN * 64 + 255) / 256, 256, 0, stream>>>(x, node_W, node_b, h, hb, NN);

    for (int i = 0; i < NL; ++i) {
        if (use_emb) {
            agg_emb_kernel<<<(NN + 3) / 4, 256, 0, stream>>>(
                h, hb, srcs, row_start, emb, zin);
        } else {
            agg_recompute_kernel<<<(NN + 3) / 4, 256, 0, stream>>>(
                h, hb, srcs, row_start, ea_s, edge_W, edge_b, zin);
        }
        fused_layer_kernel<<<(NN + 63) / 64, 256, 0, stream>>>(
            zin, wb + (size_t)i * HD * HD, lin1_b + i * HD,
            bn_gamma + i * HD, bn_beta + i * HD, bn_mean + i * HD, bn_var + i * HD,
            wb + (size_t)(3 + i) * HD * HD, lin2_b + i * HD,
            h, (ushort*)hb, NN);
    }

    hipMemsetAsync(pooled, 0, NG * HD * sizeof(float), stream);
    hipMemsetAsync(counts, 0, NG * sizeof(int), stream);
    pool_kernel<<<(NN + 31) / 32, 128, 0, stream>>>(h, batch, pooled, counts, NN, 32);
    final_kernel<<<NG, HD, 0, stream>>>(pooled, counts, projT, proj_b, (float*)d_out);
}

// Round 6
// 480.176 us; speedup vs baseline: 5.0447x; 1.0163x over previous
//
#include <hip/hip_runtime.h>

typedef unsigned int uint;
typedef unsigned short ushort;
typedef unsigned char uchar;
typedef __attribute__((ext_vector_type(8))) short bf16x8;
typedef __attribute__((ext_vector_type(4))) float f32x4;

#define NN 50000
#define NE 800000
#define NG 64
#define NODE_F 11
#define EDGE_F 14
#define HD 128
#define NL 3
#define BN_EPS 1e-5f

#if defined(__has_builtin)
#if __has_builtin(__builtin_amdgcn_cvt_f32_fp8) && __has_builtin(__builtin_amdgcn_cvt_pk_fp8_f32)
#define HW_FP8 1
#endif
#endif

__device__ __forceinline__ uint bfround(float v) {
    uint b = __float_as_uint(v);
    return (b + 0x7fffu + ((b >> 16) & 1u)) >> 16;
}

#ifndef HW_FP8
// ---- manual OCP e4m3 encode (RNE, clamp 448) + decode, used only if no HW cvt ----
__device__ __forceinline__ uint f8enc(float v) {
    float a = fabsf(v);
    uint s = (__float_as_uint(v) >> 31) << 7;
    if (!(a > 0.f)) return s;
    if (a >= 448.f) return s | 0x7e;
    uint ab = __float_as_uint(a);
    int e = (int)(ab >> 23) - 127;
    uint m = ab & 0x7fffffu;
    if (e < -6) {
        if (e < -10) return s;
        uint full = 0x800000u | m;
        int shift = 14 - e;  // 21..24
        uint q = full >> shift;
        uint rem = full & ((1u << shift) - 1u);
        uint half = 1u << (shift - 1);
        if (rem > half || (rem == half && (q & 1))) q++;
        return s | q;        // q==8 naturally becomes min normal 0x08
    }
    uint m3 = m >> 20;
    uint rem = m & 0xfffffu;
    if (rem > 0x80000u || (rem == 0x80000u && (m3 & 1))) {
        m3++;
        if (m3 == 8) { m3 = 0; e++; }
    }
    if (e > 8 || (e == 8 && m3 > 6)) return s | 0x7e;
    return s | ((uint)(e + 7) << 3) | m3;
}
__device__ __forceinline__ float f8dec(uint x) {
    uint e = (x >> 3) & 15u, m = x & 7u;
    float v = (e == 0) ? ldexpf((float)m, -9) : ldexpf((float)(8u + m), (int)e - 10);
    return (x & 0x80u) ? -v : v;
}
#endif

// ------- init: prep weights (blocks 0..447) + node embedding (rest) --------
__global__ __launch_bounds__(256)
void init_kernel(const float* __restrict__ x, const float* __restrict__ nW,
                 const float* __restrict__ nb_, const float* __restrict__ lin1,
                 const float* __restrict__ lin2, const float* __restrict__ proj,
                 float* __restrict__ h, uint* __restrict__ hb,
                 ushort* __restrict__ wb, float* __restrict__ projT)
{
    int bid = blockIdx.x;
    if (bid < 448) {
        int idx = bid * 256 + threadIdx.x;
        if (idx >= 7 * HD * HD) return;
        if (idx < 6 * HD * HD) {
            int m = idx >> 14, e = idx & (HD * HD - 1);
            const float* src = (m < 3) ? (lin1 + m * HD * HD) : (lin2 + (m - 3) * HD * HD);
            wb[idx] = (ushort)bfround(src[e]);
        } else {
            int e = idx - 6 * HD * HD;
            int r = e >> 7, c = e & 127;
            projT[c * HD + r] = proj[r * HD + c];
        }
    } else {
        int idx = (bid - 448) * 256 + threadIdx.x;
        if (idx >= NN * 64) return;
        int node = idx >> 6, cp = idx & 63;
        int c2 = cp * 2;
        const float* xr = x + node * NODE_F;
        const float* w0 = nW + c2 * NODE_F;
        const float* w1 = w0 + NODE_F;
        float a0 = nb_[c2], a1 = nb_[c2 + 1];
#pragma unroll
        for (int f = 0; f < NODE_F; ++f) { float xv = xr[f]; a0 += xv * w0[f]; a1 += xv * w1[f]; }
        *(float2*)&h[(size_t)node * HD + c2] = make_float2(a0, a1);
        hb[idx] = bfround(a0) | (bfround(a1) << 16);
    }
}

// ----------------------------- CSR construction ----------------------------
__global__ __launch_bounds__(256)
void hist_kernel(const int* __restrict__ ei, int* __restrict__ deg)
{
    int e = blockIdx.x * 256 + threadIdx.x;
    if (e < NE) atomicAdd(&deg[ei[NE + e]], 1);
}

__global__ __launch_bounds__(256)
void scan1_kernel(const int* __restrict__ deg, int* __restrict__ incl, int* __restrict__ bsum)
{
    int i = blockIdx.x * 256 + threadIdx.x;
    int v = (i < NN) ? deg[i] : 0;
    int lane = threadIdx.x & 63;
#pragma unroll
    for (int off = 1; off < 64; off <<= 1) {
        int u = __shfl_up(v, off);
        if (lane >= off) v += u;
    }
    __shared__ int wsum[4];
    if (lane == 63) wsum[threadIdx.x >> 6] = v;
    __syncthreads();
    int wid = threadIdx.x >> 6;
    int add = 0;
#pragma unroll
    for (int w = 0; w < 3; ++w) if (w < wid) add += wsum[w];
    v += add;
    if (i < NN) incl[i] = v;
    if (threadIdx.x == 255) bsum[blockIdx.x] = v;
}

__global__ __launch_bounds__(256)
void scan2_kernel(const int* __restrict__ bsum, int* __restrict__ bscan, int nb)
{
    int i = threadIdx.x;
    int v = (i < nb) ? bsum[i] : 0;
    int lane = i & 63;
#pragma unroll
    for (int off = 1; off < 64; off <<= 1) {
        int u = __shfl_up(v, off);
        if (lane >= off) v += u;
    }
    __shared__ int wsum[4];
    if (lane == 63) wsum[i >> 6] = v;
    __syncthreads();
    int wid = i >> 6;
    int add = 0;
#pragma unroll
    for (int w = 0; w < 3; ++w) if (w < wid) add += wsum[w];
    v += add;
    bscan[i] = v;
}

__global__ __launch_bounds__(256)
void scan3_kernel(const int* __restrict__ deg, const int* __restrict__ incl,
                  const int* __restrict__ bscan, int* __restrict__ row_start,
                  int* __restrict__ cursor)
{
    int i = blockIdx.x * 256 + threadIdx.x;
    if (i >= NN) return;
    int b = blockIdx.x;
    int base = (b > 0) ? bscan[b - 1] : 0;
    int rs = base + incl[i] - deg[i];
    row_start[i] = rs;
    cursor[i] = rs;
    if (i == 0) row_start[NN] = NE;
}

__global__ __launch_bounds__(256)
void scatter_kernel(const int* __restrict__ ei, int* __restrict__ cursor,
                    int* __restrict__ srcs, int* __restrict__ eid)
{
    int e = blockIdx.x * 256 + threadIdx.x;
    if (e >= NE) return;
    int s = ei[e], d = ei[NE + e];
    int pos = atomicAdd(&cursor[d], 1);
    srcs[pos] = s;
    eid[pos] = e;
}

// -- one-time: emb[j] = fp8(edge_attr[eid[j]] @ eW^T + eb), dst-sorted order --
__global__ __launch_bounds__(256)
void embed_edges_kernel(const float* __restrict__ ea, const int* __restrict__ eid,
                        const float* __restrict__ eW, const float* __restrict__ eb,
                        uchar* __restrict__ emb)
{
    const int EC = 64;
    int wv = blockIdx.x * 4 + (threadIdx.x >> 6);
    int j0 = wv * EC;
    if (j0 >= NE) return;
    int lane = threadIdx.x & 63;
    int c2 = lane * 2;
    float w0[EDGE_F], w1[EDGE_F];
    {
        const float* p = eW + c2 * EDGE_F;
#pragma unroll
        for (int f = 0; f < EDGE_F; ++f) { w0[f] = p[f]; w1[f] = p[EDGE_F + f]; }
    }
    float bx = eb[c2], by = eb[c2 + 1];
    int jend = min(j0 + EC, NE);
    for (int j = j0; j < jend; ++j) {
        int e = __builtin_amdgcn_readfirstlane(eid[j]);
        const float2* er = (const float2*)(ea + (size_t)e * EDGE_F);
        float ax = bx, ay = by;
#pragma unroll
        for (int f2 = 0; f2 < 7; ++f2) {
            float2 av = er[f2];
            ax += av.x * w0[2 * f2] + av.y * w0[2 * f2 + 1];
            ay += av.x * w1[2 * f2] + av.y * w1[2 * f2 + 1];
        }
        ushort st;
#ifdef HW_FP8
        uint pk = (uint)__builtin_amdgcn_cvt_pk_fp8_f32(ax, ay, 0, false);
        st = (ushort)(pk & 0xffffu);
#else
        st = (ushort)(f8enc(ax) | (f8enc(ay) << 8));
#endif
        *(ushort*)(emb + (size_t)j * HD + c2) = st;
    }
}

// ------ agg (fp8 emb): zin[n] = h[n] + sum_j relu(hb[src_j] + emb[j]) ------
#ifdef HW_FP8
#define DEC2(EV, EX, EY)                                                    \
    float EX = __builtin_amdgcn_cvt_f32_fp8((int)(EV), 0);                  \
    float EY = __builtin_amdgcn_cvt_f32_fp8((int)(EV), 1);
#else
#define DEC2(EV, EX, EY)                                                    \
    float EX = lut[(EV) & 0xff];                                            \
    float EY = lut[((EV) >> 8) & 0xff];
#endif

#define MSGF(HV, EX, EY)                                                    \
    {                                                                       \
        float hx = __uint_as_float((HV) << 16);                             \
        float hy = __uint_as_float((HV) & 0xffff0000u);                     \
        accx += fmaxf(hx + (EX), 0.f);                                      \
        accy += fmaxf(hy + (EY), 0.f);                                      \
    }

__global__ __launch_bounds__(256)
void agg_emb_kernel(const float* __restrict__ h, const uint* __restrict__ hb,
                    const int* __restrict__ srcs, const int* __restrict__ row_start,
                    const uchar* __restrict__ emb, float* __restrict__ zin)
{
#ifndef HW_FP8
    __shared__ float lut[256];
    lut[threadIdx.x & 255] = f8dec(threadIdx.x & 255);
    __syncthreads();
#endif
    int node = blockIdx.x * 4 + (threadIdx.x >> 6);
    if (node >= NN) return;
    int lane = threadIdx.x & 63;
    int c2 = lane * 2;
    float accx = 0.f, accy = 0.f;
    int beg = __builtin_amdgcn_readfirstlane(row_start[node]);
    int end = __builtin_amdgcn_readfirstlane(row_start[node + 1]);
    int j = beg;
    for (; j + 4 <= end; j += 4) {
        int s0 = srcs[j], s1 = srcs[j + 1], s2 = srcs[j + 2], s3 = srcs[j + 3];
        uint hv0 = hb[(size_t)s0 * 64 + lane];
        uint hv1 = hb[(size_t)s1 * 64 + lane];
        uint hv2 = hb[(size_t)s2 * 64 + lane];
        uint hv3 = hb[(size_t)s3 * 64 + lane];
        uint ev0 = *(const ushort*)(emb + (size_t)j * HD + c2);
        uint ev1 = *(const ushort*)(emb + (size_t)(j + 1) * HD + c2);
        uint ev2 = *(const ushort*)(emb + (size_t)(j + 2) * HD + c2);
        uint ev3 = *(const ushort*)(emb + (size_t)(j + 3) * HD + c2);
        { DEC2(ev0, ex, ey) MSGF(hv0, ex, ey) }
        { DEC2(ev1, ex, ey) MSGF(hv1, ex, ey) }
        { DEC2(ev2, ex, ey) MSGF(hv2, ex, ey) }
        { DEC2(ev3, ex, ey) MSGF(hv3, ex, ey) }
    }
    for (; j < end; ++j) {
        uint hv0 = hb[(size_t)srcs[j] * 64 + lane];
        uint ev0 = *(const ushort*)(emb + (size_t)j * HD + c2);
        { DEC2(ev0, ex, ey) MSGF(hv0, ex, ey) }
    }
    float2 hn = *(const float2*)&h[(size_t)node * HD + c2];
    *(float2*)&zin[(size_t)node * HD + c2] = make_float2(hn.x + accx, hn.y + accy);
}

// ------ agg (fallback, recompute): proven round-5 path, dst-sorted ea_s ----
#define EMSG(HV, EP)                                                       \
    {                                                                      \
        float ax = bx, ay = by;                                            \
        _Pragma("unroll")                                                  \
        for (int f2 = 0; f2 < 7; ++f2) {                                   \
            float2 av = (EP)[f2];                                          \
            ax += av.x * w0[2 * f2] + av.y * w0[2 * f2 + 1];               \
            ay += av.x * w1[2 * f2] + av.y * w1[2 * f2 + 1];               \
        }                                                                  \
        float hx = __uint_as_float((HV) << 16);                            \
        float hy = __uint_as_float((HV) & 0xffff0000u);                    \
        accx += fmaxf(hx + ax, 0.f);                                       \
        accy += fmaxf(hy + ay, 0.f);                                       \
    }

__global__ __launch_bounds__(256)
void permute_ea_kernel(const float* __restrict__ ea, const int* __restrict__ eid,
                       float* __restrict__ ea_s)
{
    int idx = blockIdx.x * 256 + threadIdx.x;
    if (idx >= NE * 7) return;
    int e = idx / 7, f2 = idx % 7;
    float2 v = *(const float2*)(ea + (size_t)eid[e] * EDGE_F + f2 * 2);
    *(float2*)(ea_s + (size_t)e * EDGE_F + f2 * 2) = v;
}

__global__ __launch_bounds__(256)
void agg_recompute_kernel(const float* __restrict__ h, const uint* __restrict__ hb,
                          const int* __restrict__ srcs, const int* __restrict__ row_start,
                          const float* __restrict__ ea_s, const float* __restrict__ eW,
                          const float* __restrict__ eb, float* __restrict__ zin)
{
    int node = blockIdx.x * 4 + (threadIdx.x >> 6);
    if (node >= NN) return;
    int lane = threadIdx.x & 63;
    int c2 = lane * 2;
    float w0[EDGE_F], w1[EDGE_F];
    {
        const float* p = eW + c2 * EDGE_F;
#pragma unroll
        for (int f = 0; f < EDGE_F; ++f) { w0[f] = p[f]; w1[f] = p[EDGE_F + f]; }
    }
    float bx = eb[c2], by = eb[c2 + 1];
    float accx = 0.f, accy = 0.f;
    int beg = __builtin_amdgcn_readfirstlane(row_start[node]);
    int end = __builtin_amdgcn_readfirstlane(row_start[node + 1]);
    int j = beg;
    for (; j + 4 <= end; j += 4) {
        int s0 = srcs[j], s1 = srcs[j + 1], s2 = srcs[j + 2], s3 = srcs[j + 3];
        uint hv0 = hb[(size_t)s0 * 64 + lane];
        uint hv1 = hb[(size_t)s1 * 64 + lane];
        uint hv2 = hb[(size_t)s2 * 64 + lane];
        uint hv3 = hb[(size_t)s3 * 64 + lane];
        const float2* e0 = (const float2*)(ea_s + (size_t)j * EDGE_F);
        const float2* e1 = e0 + 7;
        const float2* e2 = e0 + 14;
        const float2* e3 = e0 + 21;
        EMSG(hv0, e0); EMSG(hv1, e1); EMSG(hv2, e2); EMSG(hv3, e3);
    }
    for (; j < end; ++j) {
        uint hv0 = hb[(size_t)srcs[j] * 64 + lane];
        const float2* e0 = (const float2*)(ea_s + (size_t)j * EDGE_F);
        EMSG(hv0, e0);
    }
    float2 hn = *(const float2*)&h[(size_t)node * HD + c2];
    *(float2*)&zin[(size_t)node * HD + c2] = make_float2(hn.x + accx, hn.y + accy);
}

// --------- fused layer: h = relu(relu(BN(zin@W1^T+b1))@W2^T+b2) + h --------
__global__ __launch_bounds__(256)
void fused_layer_kernel(const float* __restrict__ zin,
                        const ushort* __restrict__ w1b, const float* __restrict__ b1,
                        const float* __restrict__ gamma, const float* __restrict__ beta,
                        const float* __restrict__ mean, const float* __restrict__ var,
                        const ushort* __restrict__ w2b, const float* __restrict__ b2,
                        float* __restrict__ h, ushort* __restrict__ hb, int n)
{
    __shared__ uint Ahi[64 * 64];  // bf16[64][128], XOR-swizzled; reused for z
    __shared__ uint Alo[64 * 64];
    const int t = threadIdx.x;
    const int nb = blockIdx.x * 64;

    {
        int row = t >> 2;
        int kq = (t & 3) * 32;
        int gn = nb + row;
        uint hiw[16], low[16];
        if (gn < n) {
            const float4* src = (const float4*)(zin + (size_t)gn * HD + kq);
#pragma unroll
            for (int i = 0; i < 8; ++i) {
                float4 v = src[i];
                uint h0 = bfround(v.x), h1 = bfround(v.y), h2 = bfround(v.z), h3 = bfround(v.w);
                float r0 = v.x - __uint_as_float(h0 << 16);
                float r1 = v.y - __uint_as_float(h1 << 16);
                float r2 = v.z - __uint_as_float(h2 << 16);
                float r3 = v.w - __uint_as_float(h3 << 16);
                hiw[2 * i]     = h0 | (h1 << 16);
                hiw[2 * i + 1] = h2 | (h3 << 16);
                low[2 * i]     = bfround(r0) | (bfround(r1) << 16);
                low[2 * i + 1] = bfround(r2) | (bfround(r3) << 16);
            }
        } else {
#pragma unroll
            for (int i = 0; i < 16; ++i) { hiw[i] = 0; low[i] = 0; }
        }
        uint rowbase = row * 256;
#pragma unroll
        for (int i = 0; i < 4; ++i) {
            uint byte = (rowbase + (kq + 8 * i) * 2) ^ ((row & 7) << 4);
            *(uint4*)((char*)Ahi + byte) = make_uint4(hiw[4 * i], hiw[4 * i + 1], hiw[4 * i + 2], hiw[4 * i + 3]);
            *(uint4*)((char*)Alo + byte) = make_uint4(low[4 * i], low[4 * i + 1], low[4 * i + 2], low[4 * i + 3]);
        }
    }

    const int w  = t >> 6, l = t & 63;
    const int lc = l & 15, lk = l >> 4;
    bf16x8 wf1[2][4], wf2[2][4];
#pragma unroll
    for (int ct = 0; ct < 2; ++ct)
#pragma unroll
        for (int ks = 0; ks < 4; ++ks) {
            size_t off = (size_t)(w * 32 + ct * 16 + lc) * HD + ks * 32 + lk * 8;
            wf1[ct][ks] = *(const bf16x8*)(w1b + off);
            wf2[ct][ks] = *(const bf16x8*)(w2b + off);
        }

    __syncthreads();

    f32x4 acc[4][2];
#pragma unroll
    for (int rt = 0; rt < 4; ++rt)
#pragma unroll
        for (int ct = 0; ct < 2; ++ct) acc[rt][ct] = (f32x4){0.f, 0.f, 0.f, 0.f};

#pragma unroll
    for (int ks = 0; ks < 4; ++ks) {
#pragma unroll
        for (int rt = 0; rt < 4; ++rt) {
            int row = rt * 16 + lc;
            uint byte = ((uint)(row * 256 + (ks * 32 + lk * 8) * 2)) ^ ((row & 7) << 4);
            bf16x8 ah = *(const bf16x8*)((char*)Ahi + byte);
            bf16x8 al = *(const bf16x8*)((char*)Alo + byte);
            acc[rt][0] = __builtin_amdgcn_mfma_f32_16x16x32_bf16(ah, wf1[0][ks], acc[rt][0], 0, 0, 0);
            acc[rt][0] = __builtin_amdgcn_mfma_f32_16x16x32_bf16(al, wf1[0][ks], acc[rt][0], 0, 0, 0);
            acc[rt][1] = __builtin_amdgcn_mfma_f32_16x16x32_bf16(ah, wf1[1][ks], acc[rt][1], 0, 0, 0);
            acc[rt][1] = __builtin_amdgcn_mfma_f32_16x16x32_bf16(al, wf1[1][ks], acc[rt][1], 0, 0, 0);
        }
    }

    __syncthreads();

#pragma unroll
    for (int ct = 0; ct < 2; ++ct) {
        int col = w * 32 + ct * 16 + lc;
        float bi = b1[col];
        float scv = gamma[col] * rsqrtf(var[col] + BN_EPS);
        float shv = beta[col] - mean[col] * scv;
#pragma unroll
        for (int rt = 0; rt < 4; ++rt) {
#pragma unroll
            for (int r = 0; r < 4; ++r) {
                int rowl = rt * 16 + lk * 4 + r;
                float v = (acc[rt][ct][r] + bi) * scv + shv;
                v = fmaxf(v, 0.f);
                uint byte = ((uint)(rowl * 256 + col * 2)) ^ ((rowl & 7) << 4);
                *(ushort*)((char*)Ahi + byte) = (ushort)bfround(v);
            }
        }
    }

    __syncthreads();

    f32x4 acc2[4][2];
#pragma unroll
    for (int rt = 0; rt < 4; ++rt)
#pragma unroll
        for (int ct = 0; ct < 2; ++ct) acc2[rt][ct] = (f32x4){0.f, 0.f, 0.f, 0.f};

#pragma unroll
    for (int ks = 0; ks < 4; ++ks) {
#pragma unroll
        for (int rt = 0; rt < 4; ++rt) {
            int row = rt * 16 + lc;
            uint byte = ((uint)(row * 256 + (ks * 32 + lk * 8) * 2)) ^ ((row & 7) << 4);
            bf16x8 az = *(const bf16x8*)((char*)Ahi + byte);
            acc2[rt][0] = __builtin_amdgcn_mfma_f32_16x16x32_bf16(az, wf2[0][ks], acc2[rt][0], 0, 0, 0);
            acc2[rt][1] = __builtin_amdgcn_mfma_f32_16x16x32_bf16(az, wf2[1][ks], acc2[rt][1], 0, 0, 0);
        }
    }

#pragma unroll
    for (int ct = 0; ct < 2; ++ct) {
        int col = w * 32 + ct * 16 + lc;
        float bi = b2[col];
#pragma unroll
        for (int rt = 0; rt < 4; ++rt) {
#pragma unroll
            for (int r = 0; r < 4; ++r) {
                int row = nb + rt * 16 + lk * 4 + r;
                if (row < n) {
                    float v = fmaxf(acc2[rt][ct][r] + bi, 0.f) + h[(size_t)row * HD + col];
                    h[(size_t)row * HD + col] = v;
                    hb[(size_t)row * HD + col] = (ushort)bfround(v);
                }
            }
        }
    }
}

// -------- pooling: sorted batch_idx -> chunked local sums, rare atomics ----
__global__ __launch_bounds__(128)
void pool_kernel(const float* __restrict__ h, const int* __restrict__ batch,
                 float* __restrict__ pooled, int* __restrict__ counts, int n, int chunk)
{
    int c = threadIdx.x;
    int n_start = blockIdx.x * chunk;
    if (n_start >= n) return;
    int n_end = min(n_start + chunk, n);
    float local = 0.f;
    int cnt = 0;
    int g_cur = batch[n_start];
    for (int nd = n_start; nd < n_end; ++nd) {
        int g = batch[nd];
        if (g != g_cur) {
            atomicAdd(&pooled[g_cur * HD + c], local);
            if (c == 0) atomicAdd(&counts[g_cur], cnt);
            local = 0.f; cnt = 0; g_cur = g;
        }
        local += h[(size_t)nd * HD + c];
        cnt++;
    }
    atomicAdd(&pooled[g_cur * HD + c], local);
    if (c == 0) atomicAdd(&counts[g_cur], cnt);
}

__global__ __launch_bounds__(128)
void final_kernel(const float* __restrict__ pooled, const int* __restrict__ counts,
                  const float* __restrict__ projT, const float* __restrict__ pb,
                  float* __restrict__ out)
{
    __shared__ float p_lds[HD];
    int g = blockIdx.x, p = threadIdx.x;
    float inv = 1.f / fmaxf((float)counts[g], 1.f);
    p_lds[p] = pooled[g * HD + p];
    __syncthreads();
    float acc = 0.f;
#pragma unroll 4
    for (int c = 0; c < HD; ++c) acc += p_lds[c] * projT[c * HD + p];
    out[g * HD + p] = acc * inv + pb[p];
}

extern "C" void kernel_launch(void* const* d_in, const int* in_sizes, int n_in,
                              void* d_out, int out_size, void* d_ws, size_t ws_size,
                              hipStream_t stream)
{
    const float* x        = (const float*)d_in[0];
    const int*   edge_idx = (const int*)d_in[1];
    const float* edge_attr= (const float*)d_in[2];
    const int*   batch    = (const int*)d_in[3];
    const float* node_W   = (const float*)d_in[4];
    const float* node_b   = (const float*)d_in[5];
    const float* edge_W   = (const float*)d_in[6];
    const float* edge_b   = (const float*)d_in[7];
    const float* lin1_b   = (const float*)d_in[9];
    const float* bn_gamma = (const float*)d_in[10];
    const float* bn_beta  = (const float*)d_in[11];
    const float* bn_mean  = (const float*)d_in[12];
    const float* bn_var   = (const float*)d_in[13];
    const float* lin2_b   = (const float*)d_in[15];
    const float* proj_b   = (const float*)d_in[17];

    char* ws = (char*)d_ws;
    float*  h        = (float*) (ws);                  // 25.6 MB
    float*  zin      = (float*) (ws + 25600000);       // 25.6 MB
    uint*   hb       = (uint*)  (ws + 51200000);       // 12.8 MB (packed bf16, 2ch/uint)
    int*    srcs     = (int*)   (ws + 64000000);       // 3.2 MB
    int*    eid      = (int*)   (ws + 67200000);       // 3.2 MB
    ushort* wb       = (ushort*)(ws + 70400000);       // 196,608
    float*  projT    = (float*) (ws + 70600000);       // 65,536
    float*  pooled   = (float*) (ws + 70700000);       // 32,768
    int*    counts   = (int*)   (ws + 70732768);       // 256 (contiguous after pooled)
    int*    deg      = (int*)   (ws + 70740000);       // 200,000
    int*    incl     = (int*)   (ws + 70940000);       // 200,000
    int*    bsum     = (int*)   (ws + 71140000);       // 1,024
    int*    bscan    = (int*)   (ws + 71142048);       // 1,024
    int*    row_start= (int*)   (ws + 71144096);       // 200,064
    int*    cursor   = (int*)   (ws + 71344160);       // 200,000
    // path-specific region at 72 MB:
    uchar*  emb      = (uchar*) (ws + 72000000);       // 102.4 MB fp8 (emb path)
    float*  ea_s     = (float*) (ws + 72000000);       // 44.8 MB (fallback path)
    const bool use_emb = (ws_size >= (size_t)174400000);

    const int NB = (NN + 255) / 256;  // 196

    // --- CSR build (edge_index constant across layers) ---
    hipMemsetAsync(deg, 0, NN * sizeof(int), stream);
    hist_kernel<<<(NE + 255) / 256, 256, 0, stream>>>(edge_idx, deg);
    scan1_kernel<<<NB, 256, 0, stream>>>(deg, incl, bsum);
    scan2_kernel<<<1, 256, 0, stream>>>(bsum, bscan, NB);
    scan3_kernel<<<NB, 256, 0, stream>>>(deg, incl, bscan, row_start, cursor);
    scatter_kernel<<<(NE + 255) / 256, 256, 0, stream>>>(edge_idx, cursor, srcs, eid);

    if (use_emb) {
        embed_edges_kernel<<<(NE / 64 + 3) / 4, 256, 0, stream>>>(
            edge_attr, eid, edge_W, edge_b, emb);
    } else {
        permute_ea_kernel<<<(NE * 7 + 255) / 256, 256, 0, stream>>>(edge_attr, eid, ea_s);
    }

    init_kernel<<<448 + (NN * 64 + 255) / 256, 256, 0, stream>>>(
        x, node_W, node_b, (const float*)d_in[8], (const float*)d_in[14],
        (const float*)d_in[16], h, hb, wb, projT);

    for (int i = 0; i < NL; ++i) {
        if (use_emb) {
            agg_emb_kernel<<<(NN + 3) / 4, 256, 0, stream>>>(
                h, hb, srcs, row_start, emb, zin);
        } else {
            agg_recompute_kernel<<<(NN + 3) / 4, 256, 0, stream>>>(
                h, hb, srcs, row_start, ea_s, edge_W, edge_b, zin);
        }
        fused_layer_kernel<<<(NN + 63) / 64, 256, 0, stream>>>(
            zin, wb + (size_t)i * HD * HD, lin1_b + i * HD,
            bn_gamma + i * HD, bn_beta + i * HD, bn_mean + i * HD, bn_var + i * HD,
            wb + (size_t)(3 + i) * HD * HD, lin2_b + i * HD,
            h, (ushort*)hb, NN);
    }

    hipMemsetAsync(pooled, 0, NG * HD * sizeof(float) + NG * sizeof(int) + 4000, stream);
    pool_kernel<<<(NN + 31) / 32, 128, 0, stream>>>(h, batch, pooled, counts, NN, 32);
    final_kernel<<<NG, HD, 0, stream>>>(pooled, counts, projT, proj_b, (float*)d_out);
}